// Round 2
// baseline (1379.957 us; speedup 1.0000x reference)
//
#include <hip/hip_runtime.h>
#include <math.h>

#define HD 128
#define NPB 16   // nodes per block (node kernel)
#define RPT 8    // rows per thread-group

// Phase 1: S[dst[e]] += h[src[e]]  (32 lanes per edge, float4 per lane) + degree count
__global__ __launch_bounds__(256) void mpnn_scatter(
    const float* __restrict__ h,
    const int* __restrict__ src,
    const int* __restrict__ dst,
    float* __restrict__ S,
    int* __restrict__ deg,
    int n_edges)
{
    int gid = blockIdx.x * 256 + threadIdx.x;
    int e = gid >> 5;
    if (e >= n_edges) return;
    int lane = gid & 31;
    int s = src[e];
    int d = dst[e];
    float4 v = *(const float4*)(h + (size_t)s * HD + lane * 4);
    float* srow = S + (size_t)d * HD + lane * 4;
    atomicAdd(srow + 0, v.x);
    atomicAdd(srow + 1, v.y);
    atomicAdd(srow + 2, v.z);
    atomicAdd(srow + 3, v.w);
    if (lane == 0) atomicAdd(deg + d, 1);
}

// Phase 2 (in-place on S=d_out):
//   out[n][j] = sigmoid( S[n]@W1[:,j] + deg[n]*(h[n]@W2[:,j] + b[j]) ) + softplus(h[n][j])
__global__ __launch_bounds__(256) void mpnn_node(
    const float* __restrict__ h,
    const float* __restrict__ W,   // [256][128] row-major
    const float* __restrict__ b,   // [128]
    const int* __restrict__ deg,
    float* __restrict__ S,         // in: scatter sums; out: final output
    int n_nodes)
{
    const int j = threadIdx.x & (HD - 1);
    const int g = threadIdx.x >> 7;          // 0..1
    const int n0 = blockIdx.x * NPB + g * RPT;

    float accS[RPT], accH[RPT];
    #pragma unroll
    for (int r = 0; r < RPT; ++r) { accS[r] = 0.f; accH[r] = 0.f; }

    int rmax = n_nodes - n0;
    if (rmax > RPT) rmax = RPT;
    if (rmax < 0) rmax = 0;

    // S @ W1   (W rows 0..127)
    for (int k = 0; k < HD; k += 4) {
        float w0 = W[(k + 0) * HD + j];
        float w1 = W[(k + 1) * HD + j];
        float w2 = W[(k + 2) * HD + j];
        float w3 = W[(k + 3) * HD + j];
        #pragma unroll
        for (int r = 0; r < RPT; ++r) {
            if (r < rmax) {
                float4 a = *(const float4*)(S + (size_t)(n0 + r) * HD + k);
                accS[r] = fmaf(a.x, w0, accS[r]);
                accS[r] = fmaf(a.y, w1, accS[r]);
                accS[r] = fmaf(a.z, w2, accS[r]);
                accS[r] = fmaf(a.w, w3, accS[r]);
            }
        }
    }
    // h @ W2   (W rows 128..255)
    for (int k = 0; k < HD; k += 4) {
        float w0 = W[(HD + k + 0) * HD + j];
        float w1 = W[(HD + k + 1) * HD + j];
        float w2 = W[(HD + k + 2) * HD + j];
        float w3 = W[(HD + k + 3) * HD + j];
        #pragma unroll
        for (int r = 0; r < RPT; ++r) {
            if (r < rmax) {
                float4 a = *(const float4*)(h + (size_t)(n0 + r) * HD + k);
                accH[r] = fmaf(a.x, w0, accH[r]);
                accH[r] = fmaf(a.y, w1, accH[r]);
                accH[r] = fmaf(a.z, w2, accH[r]);
                accH[r] = fmaf(a.w, w3, accH[r]);
            }
        }
    }

    // all S reads done before any S writes within this block's rows
    __syncthreads();

    #pragma unroll
    for (int r = 0; r < RPT; ++r) {
        if (r < rmax) {
            int n = n0 + r;
            float dg = (float)deg[n];
            float agg = accS[r] + dg * (accH[r] + b[j]);
            float hv = h[(size_t)n * HD + j];
            float sp = fmaxf(hv, 0.f) + log1pf(expf(-fabsf(hv)));   // stable softplus
            float sg = 1.f / (1.f + expf(-agg));                    // sigmoid
            S[(size_t)n * HD + j] = sg + sp;
        }
    }
}

extern "C" void kernel_launch(void* const* d_in, const int* in_sizes, int n_in,
                              void* d_out, int out_size, void* d_ws, size_t ws_size,
                              hipStream_t stream)
{
    const float* h   = (const float*)d_in[0];
    const int*   src = (const int*)d_in[1];
    const int*   dst = (const int*)d_in[2];
    const float* W   = (const float*)d_in[3];
    const float* b   = (const float*)d_in[4];
    float* S  = (float*)d_out;
    int* deg  = (int*)d_ws;

    const int n_nodes = in_sizes[0] / HD;
    const int n_edges = in_sizes[1];

    // zero accumulators every call (harness poisons once, never re-poisons)
    hipMemsetAsync(d_out, 0, (size_t)n_nodes * HD * sizeof(float), stream);
    hipMemsetAsync(d_ws, 0, (size_t)n_nodes * sizeof(int), stream);

    const int sblocks = (int)(((long long)n_edges * 32 + 255) / 256);
    mpnn_scatter<<<sblocks, 256, 0, stream>>>(h, src, dst, S, deg, n_edges);

    const int nblocks = (n_nodes + NPB - 1) / NPB;
    mpnn_node<<<nblocks, 256, 0, stream>>>(h, W, b, deg, S, n_nodes);
}

// Round 3
// 432.776 us; speedup vs baseline: 3.1886x; 3.1886x over previous
//
#include <hip/hip_runtime.h>
#include <math.h>

#define HD 128
#define NPB 16   // nodes per block (node kernel)
#define RPT 8    // rows per thread-group

// ---------------- CSR build ----------------

__global__ __launch_bounds__(256) void edge_hist(
    const int* __restrict__ dst, int* __restrict__ deg, int n_edges)
{
    int e = blockIdx.x * 256 + threadIdx.x;
    if (e < n_edges) atomicAdd(&deg[dst[e]], 1);
}

// single-block exclusive scan of deg -> off (and cur copy); off[n_nodes] = n_edges
__global__ __launch_bounds__(1024) void scan_deg(
    const int* __restrict__ deg, int* __restrict__ off, int* __restrict__ cur,
    int n_nodes, int n_edges)
{
    __shared__ int wtot[16];
    __shared__ int carry_s;
    const int t = threadIdx.x;
    const int lane = t & 63;
    const int wid = t >> 6;
    if (t == 0) carry_s = 0;
    __syncthreads();

    for (int base = 0; base < n_nodes; base += 1024) {
        int idx = base + t;
        int v = (idx < n_nodes) ? deg[idx] : 0;
        int incl = v;
        #pragma unroll
        for (int o = 1; o < 64; o <<= 1) {
            int y = __shfl_up(incl, o, 64);
            if (lane >= o) incl += y;
        }
        if (lane == 63) wtot[wid] = incl;
        __syncthreads();                      // (A) wtot filled
        if (wid == 0) {
            int w = (lane < 16) ? wtot[lane] : 0;
            int wi = w;
            #pragma unroll
            for (int o = 1; o < 16; o <<= 1) {
                int y = __shfl_up(wi, o, 64);
                if (lane >= o) wi += y;
            }
            if (lane < 16) wtot[lane] = wi - w;  // exclusive wave offsets
        }
        __syncthreads();                      // (B) wtot exclusive ready
        int carry = carry_s;
        int excl = carry + wtot[wid] + incl - v;
        if (idx < n_nodes) { off[idx] = excl; cur[idx] = excl; }
        __syncthreads();                      // (C) everyone consumed carry_s/wtot
        if (t == 1023) carry_s = carry + wtot[15] + incl;  // chunk total
        __syncthreads();                      // (D) carry_s visible, wtot reusable
    }
    if (t == 0) off[n_nodes] = n_edges;
}

__global__ __launch_bounds__(256) void edge_fill(
    const int* __restrict__ src, const int* __restrict__ dst,
    int* __restrict__ cur, int* __restrict__ elist, int n_edges)
{
    int e = blockIdx.x * 256 + threadIdx.x;
    if (e < n_edges) {
        int d = dst[e];
        int pos = atomicAdd(&cur[d], 1);
        elist[pos] = src[e];
    }
}

// ---------------- gather-sum: S[n] = sum_{e: dst[e]=n} h[src[e]] ----------------

__global__ __launch_bounds__(256) void node_gather(
    const float* __restrict__ h, const int* __restrict__ off,
    const int* __restrict__ elist, float* __restrict__ S, int n_nodes)
{
    int g = (blockIdx.x * 256 + threadIdx.x) >> 5;   // node index
    int lane = threadIdx.x & 31;
    if (g >= n_nodes) return;
    int beg = off[g], end = off[g + 1];
    float4 acc = {0.f, 0.f, 0.f, 0.f};
    int i = beg;
    int s0 = (i < end) ? elist[i] : 0;               // 2-deep index pipeline
    for (; i < end; ++i) {
        int s1 = (i + 1 < end) ? elist[i + 1] : 0;
        float4 v = *(const float4*)(h + (size_t)s0 * HD + lane * 4);
        s0 = s1;
        acc.x += v.x; acc.y += v.y; acc.z += v.z; acc.w += v.w;
    }
    *(float4*)(S + (size_t)g * HD + lane * 4) = acc;
}

// ---------------- fallback atomic scatter (small-ws path) ----------------

__global__ __launch_bounds__(256) void mpnn_scatter(
    const float* __restrict__ h, const int* __restrict__ src,
    const int* __restrict__ dst, float* __restrict__ S,
    int* __restrict__ deg, int n_edges)
{
    int gid = blockIdx.x * 256 + threadIdx.x;
    int e = gid >> 5;
    if (e >= n_edges) return;
    int lane = gid & 31;
    int s = src[e];
    int d = dst[e];
    float4 v = *(const float4*)(h + (size_t)s * HD + lane * 4);
    float* srow = S + (size_t)d * HD + lane * 4;
    atomicAdd(srow + 0, v.x);
    atomicAdd(srow + 1, v.y);
    atomicAdd(srow + 2, v.z);
    atomicAdd(srow + 3, v.w);
    if (lane == 0) atomicAdd(deg + d, 1);
}

// ---------------- node apply ----------------
//   out[n][j] = sigmoid( S[n]@W1[:,j] + deg[n]*(h[n]@W2[:,j] + b[j]) ) + softplus(h[n][j])
__global__ __launch_bounds__(256) void mpnn_node(
    const float* __restrict__ h,
    const float* __restrict__ W,   // [256][128] row-major
    const float* __restrict__ b,   // [128]
    const int* __restrict__ off,   // offsets (deg = off[n+1]-off[n]); or deg array if use_deg
    int use_deg,
    float* __restrict__ S,         // in: scatter sums; out: final output
    int n_nodes)
{
    const int j = threadIdx.x & (HD - 1);
    const int g = threadIdx.x >> 7;          // 0..1
    const int n0 = blockIdx.x * NPB + g * RPT;

    float accS[RPT], accH[RPT];
    #pragma unroll
    for (int r = 0; r < RPT; ++r) { accS[r] = 0.f; accH[r] = 0.f; }

    int rmax = n_nodes - n0;
    if (rmax > RPT) rmax = RPT;
    if (rmax < 0) rmax = 0;

    // S @ W1   (W rows 0..127)
    for (int k = 0; k < HD; k += 4) {
        float w0 = W[(k + 0) * HD + j];
        float w1 = W[(k + 1) * HD + j];
        float w2 = W[(k + 2) * HD + j];
        float w3 = W[(k + 3) * HD + j];
        #pragma unroll
        for (int r = 0; r < RPT; ++r) {
            if (r < rmax) {
                float4 a = *(const float4*)(S + (size_t)(n0 + r) * HD + k);
                accS[r] = fmaf(a.x, w0, accS[r]);
                accS[r] = fmaf(a.y, w1, accS[r]);
                accS[r] = fmaf(a.z, w2, accS[r]);
                accS[r] = fmaf(a.w, w3, accS[r]);
            }
        }
    }
    // h @ W2   (W rows 128..255)
    for (int k = 0; k < HD; k += 4) {
        float w0 = W[(HD + k + 0) * HD + j];
        float w1 = W[(HD + k + 1) * HD + j];
        float w2 = W[(HD + k + 2) * HD + j];
        float w3 = W[(HD + k + 3) * HD + j];
        #pragma unroll
        for (int r = 0; r < RPT; ++r) {
            if (r < rmax) {
                float4 a = *(const float4*)(h + (size_t)(n0 + r) * HD + k);
                accH[r] = fmaf(a.x, w0, accH[r]);
                accH[r] = fmaf(a.y, w1, accH[r]);
                accH[r] = fmaf(a.z, w2, accH[r]);
                accH[r] = fmaf(a.w, w3, accH[r]);
            }
        }
    }

    __syncthreads();   // all S reads done before any S writes in this block

    #pragma unroll
    for (int r = 0; r < RPT; ++r) {
        if (r < rmax) {
            int n = n0 + r;
            float dg = use_deg ? (float)off[n] : (float)(off[n + 1] - off[n]);
            float agg = accS[r] + dg * (accH[r] + b[j]);
            float hv = h[(size_t)n * HD + j];
            float sp = fmaxf(hv, 0.f) + log1pf(expf(-fabsf(hv)));
            float sg = 1.f / (1.f + expf(-agg));
            S[(size_t)n * HD + j] = sg + sp;
        }
    }
}

extern "C" void kernel_launch(void* const* d_in, const int* in_sizes, int n_in,
                              void* d_out, int out_size, void* d_ws, size_t ws_size,
                              hipStream_t stream)
{
    const float* h   = (const float*)d_in[0];
    const int*   src = (const int*)d_in[1];
    const int*   dst = (const int*)d_in[2];
    const float* W   = (const float*)d_in[3];
    const float* b   = (const float*)d_in[4];
    float* S = (float*)d_out;

    const int n_nodes = in_sizes[0] / HD;
    const int n_edges = in_sizes[1];

    const size_t need = ((size_t)3 * n_nodes + 1 + n_edges) * sizeof(int);
    const int nblocks = (n_nodes + NPB - 1) / NPB;

    if (ws_size >= need) {
        // CSR path: no f32 atomics
        int* deg   = (int*)d_ws;
        int* off   = deg + n_nodes;            // n_nodes + 1
        int* cur   = off + n_nodes + 1;        // n_nodes
        int* elist = cur + n_nodes;            // n_edges

        hipMemsetAsync(deg, 0, (size_t)n_nodes * sizeof(int), stream);

        edge_hist<<<(n_edges + 255) / 256, 256, 0, stream>>>(dst, deg, n_edges);
        scan_deg<<<1, 1024, 0, stream>>>(deg, off, cur, n_nodes, n_edges);
        edge_fill<<<(n_edges + 255) / 256, 256, 0, stream>>>(src, dst, cur, elist, n_edges);

        const int gblocks = (int)(((long long)n_nodes * 32 + 255) / 256);
        node_gather<<<gblocks, 256, 0, stream>>>(h, off, elist, S, n_nodes);

        mpnn_node<<<nblocks, 256, 0, stream>>>(h, W, b, off, /*use_deg=*/0, S, n_nodes);
    } else {
        // fallback: atomic scatter
        int* deg = (int*)d_ws;
        hipMemsetAsync(d_out, 0, (size_t)n_nodes * HD * sizeof(float), stream);
        hipMemsetAsync(deg, 0, (size_t)n_nodes * sizeof(int), stream);

        const int sblocks = (int)(((long long)n_edges * 32 + 255) / 256);
        mpnn_scatter<<<sblocks, 256, 0, stream>>>(h, src, dst, S, deg, n_edges);
        mpnn_node<<<nblocks, 256, 0, stream>>>(h, W, b, deg, /*use_deg=*/1, S, n_nodes);
    }
}

// Round 4
// 248.591 us; speedup vs baseline: 5.5511x; 1.7409x over previous
//
#include <hip/hip_runtime.h>
#include <math.h>

#define HD 128
#define NPB 16
#define RPT 8

typedef __attribute__((ext_vector_type(8))) short bf16x8;
typedef __attribute__((ext_vector_type(4))) float f32x4;

__device__ inline short f2bf(float x) {   // RTNE f32->bf16
    union { float f; unsigned u; } v; v.f = x;
    unsigned r = v.u + 0x7fff + ((v.u >> 16) & 1);
    return (short)(r >> 16);
}

// ---------------- CSR build ----------------

__global__ __launch_bounds__(256) void edge_hist(
    const int* __restrict__ dst, int* __restrict__ deg, int n_edges)
{
    int e = blockIdx.x * 256 + threadIdx.x;
    if (e < n_edges) atomicAdd(&deg[dst[e]], 1);
}

__global__ __launch_bounds__(1024) void scan_deg(
    const int* __restrict__ deg, int* __restrict__ off, int* __restrict__ cur,
    int n_nodes, int n_edges)
{
    __shared__ int wtot[16];
    __shared__ int carry_s;
    const int t = threadIdx.x;
    const int lane = t & 63;
    const int wid = t >> 6;
    if (t == 0) carry_s = 0;
    __syncthreads();

    for (int base = 0; base < n_nodes; base += 1024) {
        int idx = base + t;
        int v = (idx < n_nodes) ? deg[idx] : 0;
        int incl = v;
        #pragma unroll
        for (int o = 1; o < 64; o <<= 1) {
            int y = __shfl_up(incl, o, 64);
            if (lane >= o) incl += y;
        }
        if (lane == 63) wtot[wid] = incl;
        __syncthreads();
        if (wid == 0) {
            int w = (lane < 16) ? wtot[lane] : 0;
            int wi = w;
            #pragma unroll
            for (int o = 1; o < 16; o <<= 1) {
                int y = __shfl_up(wi, o, 64);
                if (lane >= o) wi += y;
            }
            if (lane < 16) wtot[lane] = wi - w;
        }
        __syncthreads();
        int carry = carry_s;
        int excl = carry + wtot[wid] + incl - v;
        if (idx < n_nodes) { off[idx] = excl; cur[idx] = excl; }
        __syncthreads();
        if (t == 1023) carry_s = carry + wtot[15] + incl;
        __syncthreads();
    }
    if (t == 0) off[n_nodes] = n_edges;
}

__global__ __launch_bounds__(256) void edge_fill(
    const int* __restrict__ src, const int* __restrict__ dst,
    int* __restrict__ cur, int* __restrict__ elist, int n_edges)
{
    int e = blockIdx.x * 256 + threadIdx.x;
    if (e < n_edges) {
        int d = dst[e];
        int pos = atomicAdd(&cur[d], 1);
        elist[pos] = src[e];
    }
}

// ---------------- gather-sum: S[n] = sum_{e: dst[e]=n} h[src[e]] ----------------

__global__ __launch_bounds__(256) void node_gather(
    const float* __restrict__ h, const int* __restrict__ off,
    const int* __restrict__ elist, float* __restrict__ S, int n_nodes)
{
    int g = (blockIdx.x * 256 + threadIdx.x) >> 5;
    int lane = threadIdx.x & 31;
    if (g >= n_nodes) return;
    int beg = off[g], end = off[g + 1];
    float4 acc = {0.f, 0.f, 0.f, 0.f};
    int i = beg;
    int s0 = (i < end) ? elist[i] : 0;
    for (; i < end; ++i) {
        int s1 = (i + 1 < end) ? elist[i + 1] : 0;
        float4 v = *(const float4*)(h + (size_t)s0 * HD + lane * 4);
        s0 = s1;
        acc.x += v.x; acc.y += v.y; acc.z += v.z; acc.w += v.w;
    }
    *(float4*)(S + (size_t)g * HD + lane * 4) = acc;
}

// ---------------- W repack: Wt[j][k] = bf16(W[k][j]), [128][256] ----------------

__global__ __launch_bounds__(256) void wt_convert(
    const float* __restrict__ W, short* __restrict__ Wt)
{
    int idx = blockIdx.x * 256 + threadIdx.x;   // 0 .. 128*256-1
    int j = idx >> 8;
    int k = idx & 255;
    Wt[idx] = f2bf(W[k * HD + j]);
}

// ---------------- MFMA node kernel ----------------
// agg = [S | deg*h] @ W + deg*b ; out = sigmoid(agg) + softplus(h). In-place on S.
// Wave: 16 rows x 128 cols, K=256, 64x mfma_f32_16x16x32_bf16.
// A/B frags both use k = (lane>>4)*8 + slot (consistent bijection -> exact).
// C/D: col = lane&15, row = (lane>>4)*4 + reg  [HW-verified m89/m91].
__global__ __launch_bounds__(256) void mpnn_node_mfma(
    const float* __restrict__ h,
    const short* __restrict__ Wt,    // [128][256] bf16
    const float* __restrict__ bias,  // [128] f32
    const int* __restrict__ deg,
    float* __restrict__ S,           // in: scatter sums [N][128]; out: final
    int n_nodes)
{
    const int lane = threadIdx.x & 63;
    const int wv = threadIdx.x >> 6;
    const int m0 = (blockIdx.x * 4 + wv) * 16;
    if (m0 >= n_nodes) return;
    const int row = lane & 15;
    const int g = lane >> 4;

    int mA = m0 + row;
    if (mA > n_nodes - 1) mA = n_nodes - 1;      // partial-tile clamp (reads only)
    const float dgA = (float)deg[mA];

    bf16x8 a[8];
    #pragma unroll
    for (int kf = 0; kf < 4; ++kf) {             // k 0..127 : S
        const float4* p = (const float4*)(S + (size_t)mA * HD + kf * 32 + g * 8);
        float4 x = p[0], y = p[1];
        bf16x8 t = { f2bf(x.x), f2bf(x.y), f2bf(x.z), f2bf(x.w),
                     f2bf(y.x), f2bf(y.y), f2bf(y.z), f2bf(y.w) };
        a[kf] = t;
    }
    #pragma unroll
    for (int kf = 0; kf < 4; ++kf) {             // k 128..255 : deg*h
        const float4* p = (const float4*)(h + (size_t)mA * HD + kf * 32 + g * 8);
        float4 x = p[0], y = p[1];
        bf16x8 t = { f2bf(dgA * x.x), f2bf(dgA * x.y), f2bf(dgA * x.z), f2bf(dgA * x.w),
                     f2bf(dgA * y.x), f2bf(dgA * y.y), f2bf(dgA * y.z), f2bf(dgA * y.w) };
        a[4 + kf] = t;
    }

    f32x4 acc[8];
    #pragma unroll
    for (int jt = 0; jt < 8; ++jt) acc[jt] = (f32x4){0.f, 0.f, 0.f, 0.f};

    #pragma unroll
    for (int jt = 0; jt < 8; ++jt) {
        const short* wj = Wt + (size_t)(jt * 16 + row) * 256 + g * 8;
        #pragma unroll
        for (int kf = 0; kf < 8; ++kf) {
            bf16x8 bf = *(const bf16x8*)(wj + kf * 32);
            acc[jt] = __builtin_amdgcn_mfma_f32_16x16x32_bf16(a[kf], bf, acc[jt], 0, 0, 0);
        }
    }

    // epilogue: lane's output rows n = m0 + g*4 + r, col = jt*16 + row
    const int nBase = m0 + g * 4;
    float dgO[4];
    #pragma unroll
    for (int r = 0; r < 4; ++r) {
        int n = nBase + r;
        dgO[r] = (n < n_nodes) ? (float)deg[n] : 0.f;
    }
    #pragma unroll
    for (int jt = 0; jt < 8; ++jt) {
        const int col = jt * 16 + row;
        const float bc = bias[col];
        #pragma unroll
        for (int r = 0; r < 4; ++r) {
            int n = nBase + r;
            if (n < n_nodes) {
                float agg = acc[jt][r] + dgO[r] * bc;
                float hv = h[(size_t)n * HD + col];
                float sp = fmaxf(hv, 0.f) + log1pf(expf(-fabsf(hv)));
                float sg = 1.f / (1.f + expf(-agg));
                S[(size_t)n * HD + col] = sg + sp;
            }
        }
    }
}

// ---------------- fallback f32 node kernel (tiny-ws tier) ----------------

__global__ __launch_bounds__(256) void mpnn_node_f32(
    const float* __restrict__ h, const float* __restrict__ W,
    const float* __restrict__ b, const int* __restrict__ deg,
    float* __restrict__ S, int n_nodes)
{
    const int j = threadIdx.x & (HD - 1);
    const int g = threadIdx.x >> 7;
    const int n0 = blockIdx.x * NPB + g * RPT;

    float accS[RPT], accH[RPT];
    #pragma unroll
    for (int r = 0; r < RPT; ++r) { accS[r] = 0.f; accH[r] = 0.f; }

    int rmax = n_nodes - n0;
    if (rmax > RPT) rmax = RPT;
    if (rmax < 0) rmax = 0;

    for (int k = 0; k < HD; k += 4) {
        float w0 = W[(k + 0) * HD + j], w1 = W[(k + 1) * HD + j];
        float w2 = W[(k + 2) * HD + j], w3 = W[(k + 3) * HD + j];
        #pragma unroll
        for (int r = 0; r < RPT; ++r) if (r < rmax) {
            float4 a = *(const float4*)(S + (size_t)(n0 + r) * HD + k);
            accS[r] = fmaf(a.x, w0, fmaf(a.y, w1, fmaf(a.z, w2, fmaf(a.w, w3, accS[r]))));
        }
    }
    for (int k = 0; k < HD; k += 4) {
        float w0 = W[(HD + k + 0) * HD + j], w1 = W[(HD + k + 1) * HD + j];
        float w2 = W[(HD + k + 2) * HD + j], w3 = W[(HD + k + 3) * HD + j];
        #pragma unroll
        for (int r = 0; r < RPT; ++r) if (r < rmax) {
            float4 a = *(const float4*)(h + (size_t)(n0 + r) * HD + k);
            accH[r] = fmaf(a.x, w0, fmaf(a.y, w1, fmaf(a.z, w2, fmaf(a.w, w3, accH[r]))));
        }
    }
    __syncthreads();
    #pragma unroll
    for (int r = 0; r < RPT; ++r) if (r < rmax) {
        int n = n0 + r;
        float dg = (float)deg[n];
        float agg = accS[r] + dg * (accH[r] + b[j]);
        float hv = h[(size_t)n * HD + j];
        float sp = fmaxf(hv, 0.f) + log1pf(expf(-fabsf(hv)));
        S[(size_t)n * HD + j] = 1.f / (1.f + expf(-agg)) + sp;
    }
}

__global__ __launch_bounds__(256) void mpnn_scatter(
    const float* __restrict__ h, const int* __restrict__ src,
    const int* __restrict__ dst, float* __restrict__ S,
    int* __restrict__ deg, int n_edges)
{
    int gid = blockIdx.x * 256 + threadIdx.x;
    int e = gid >> 5;
    if (e >= n_edges) return;
    int lane = gid & 31;
    int s = src[e], d = dst[e];
    float4 v = *(const float4*)(h + (size_t)s * HD + lane * 4);
    float* srow = S + (size_t)d * HD + lane * 4;
    atomicAdd(srow + 0, v.x);
    atomicAdd(srow + 1, v.y);
    atomicAdd(srow + 2, v.z);
    atomicAdd(srow + 3, v.w);
    if (lane == 0) atomicAdd(deg + d, 1);
}

extern "C" void kernel_launch(void* const* d_in, const int* in_sizes, int n_in,
                              void* d_out, int out_size, void* d_ws, size_t ws_size,
                              hipStream_t stream)
{
    const float* h   = (const float*)d_in[0];
    const int*   src = (const int*)d_in[1];
    const int*   dst = (const int*)d_in[2];
    const float* W   = (const float*)d_in[3];
    const float* b   = (const float*)d_in[4];
    float* S = (float*)d_out;

    const int n_nodes = in_sizes[0] / HD;
    const int n_edges = in_sizes[1];
    const int WT_INTS = 2 * HD * HD / 2;   // 32768 shorts = 16384 ints

    const size_t need_full = ((size_t)3 * n_nodes + 1 + n_edges + WT_INTS) * sizeof(int);
    const size_t need_mid  = ((size_t)n_nodes + WT_INTS) * sizeof(int);
    const int mblocks = (n_nodes + 63) / 64;         // MFMA node kernel grid

    if (ws_size >= need_full) {
        // CSR + MFMA
        int* deg   = (int*)d_ws;
        int* off   = deg + n_nodes;
        int* cur   = off + n_nodes + 1;
        int* elist = cur + n_nodes;
        short* Wt  = (short*)(elist + n_edges);

        hipMemsetAsync(deg, 0, (size_t)n_nodes * sizeof(int), stream);
        wt_convert<<<(2 * HD * HD) / 256, 256, 0, stream>>>(W, Wt);
        edge_hist<<<(n_edges + 255) / 256, 256, 0, stream>>>(dst, deg, n_edges);
        scan_deg<<<1, 1024, 0, stream>>>(deg, off, cur, n_nodes, n_edges);
        edge_fill<<<(n_edges + 255) / 256, 256, 0, stream>>>(src, dst, cur, elist, n_edges);

        const int gblocks = (int)(((long long)n_nodes * 32 + 255) / 256);
        node_gather<<<gblocks, 256, 0, stream>>>(h, off, elist, S, n_nodes);

        mpnn_node_mfma<<<mblocks, 256, 0, stream>>>(h, Wt, b, deg, S, n_nodes);
    } else if (ws_size >= need_mid) {
        // atomic scatter + MFMA
        int* deg  = (int*)d_ws;
        short* Wt = (short*)(deg + n_nodes);
        hipMemsetAsync(d_out, 0, (size_t)n_nodes * HD * sizeof(float), stream);
        hipMemsetAsync(deg, 0, (size_t)n_nodes * sizeof(int), stream);
        wt_convert<<<(2 * HD * HD) / 256, 256, 0, stream>>>(W, Wt);
        const int sblocks = (int)(((long long)n_edges * 32 + 255) / 256);
        mpnn_scatter<<<sblocks, 256, 0, stream>>>(h, src, dst, S, deg, n_edges);
        mpnn_node_mfma<<<mblocks, 256, 0, stream>>>(h, Wt, b, deg, S, n_nodes);
    } else {
        // minimal ws: atomic scatter + f32 node
        int* deg = (int*)d_ws;
        hipMemsetAsync(d_out, 0, (size_t)n_nodes * HD * sizeof(float), stream);
        hipMemsetAsync(deg, 0, (size_t)n_nodes * sizeof(int), stream);
        const int sblocks = (int)(((long long)n_edges * 32 + 255) / 256);
        mpnn_scatter<<<sblocks, 256, 0, stream>>>(h, src, dst, S, deg, n_edges);
        const int nblocks = (n_nodes + NPB - 1) / NPB;
        mpnn_node_f32<<<nblocks, 256, 0, stream>>>(h, W, b, deg, S, n_nodes);
    }
}

// Round 5
// 212.209 us; speedup vs baseline: 6.5028x; 1.1714x over previous
//
#include <hip/hip_runtime.h>
#include <math.h>

#define HD 128
#define NPB 16
#define RPT 8

typedef __attribute__((ext_vector_type(8))) short bf16x8;
typedef __attribute__((ext_vector_type(4))) float f32x4;

__device__ inline short f2bf(float x) {   // RTNE f32->bf16
    union { float f; unsigned u; } v; v.f = x;
    unsigned r = v.u + 0x7fff + ((v.u >> 16) & 1);
    return (short)(r >> 16);
}

#define LOG2E 1.4426950408889634f
#define LN2   0.6931471805599453f

__device__ inline float fast_sigmoid(float x) {
    // 1/(1+2^(-x*log2e)) : v_exp_f32 + v_rcp_f32
    return __builtin_amdgcn_rcpf(1.0f + __builtin_amdgcn_exp2f(-LOG2E * x));
}
__device__ inline float fast_softplus(float x) {
    // max(x,0) + ln(1 + 2^(-|x|*log2e)) : v_exp_f32 + v_log_f32
    float t = __builtin_amdgcn_exp2f(-LOG2E * fabsf(x));
    return fmaxf(x, 0.0f) + LN2 * __builtin_amdgcn_logf(1.0f + t);
}

// ---------------- CSR build ----------------

__global__ __launch_bounds__(256) void edge_hist(
    const int* __restrict__ dst, int* __restrict__ deg, int n_edges)
{
    int e = blockIdx.x * 256 + threadIdx.x;
    if (e < n_edges) atomicAdd(&deg[dst[e]], 1);
}

__global__ __launch_bounds__(1024) void scan_deg(
    const int* __restrict__ deg, int* __restrict__ off, int* __restrict__ cur,
    int n_nodes, int n_edges)
{
    __shared__ int wtot[16];
    __shared__ int carry_s;
    const int t = threadIdx.x;
    const int lane = t & 63;
    const int wid = t >> 6;
    if (t == 0) carry_s = 0;
    __syncthreads();

    for (int base = 0; base < n_nodes; base += 1024) {
        int idx = base + t;
        int v = (idx < n_nodes) ? deg[idx] : 0;
        int incl = v;
        #pragma unroll
        for (int o = 1; o < 64; o <<= 1) {
            int y = __shfl_up(incl, o, 64);
            if (lane >= o) incl += y;
        }
        if (lane == 63) wtot[wid] = incl;
        __syncthreads();
        if (wid == 0) {
            int w = (lane < 16) ? wtot[lane] : 0;
            int wi = w;
            #pragma unroll
            for (int o = 1; o < 16; o <<= 1) {
                int y = __shfl_up(wi, o, 64);
                if (lane >= o) wi += y;
            }
            if (lane < 16) wtot[lane] = wi - w;
        }
        __syncthreads();
        int carry = carry_s;
        int excl = carry + wtot[wid] + incl - v;
        if (idx < n_nodes) { off[idx] = excl; cur[idx] = excl; }
        __syncthreads();
        if (t == 1023) carry_s = carry + wtot[15] + incl;
        __syncthreads();
    }
    if (t == 0) off[n_nodes] = n_edges;
}

__global__ __launch_bounds__(256) void edge_fill(
    const int* __restrict__ src, const int* __restrict__ dst,
    int* __restrict__ cur, int* __restrict__ elist, int n_edges)
{
    int e = blockIdx.x * 256 + threadIdx.x;
    if (e < n_edges) {
        int d = dst[e];
        int pos = atomicAdd(&cur[d], 1);
        elist[pos] = src[e];
    }
}

// ------- gather-sum: S[n] = sum_{e: dst[e]=n} h[src[e]], 4 independent chains -------

__global__ __launch_bounds__(256) void node_gather(
    const float* __restrict__ h, const int* __restrict__ off,
    const int* __restrict__ elist, float* __restrict__ S, int n_nodes)
{
    int g = (blockIdx.x * 256 + threadIdx.x) >> 5;
    int lane = threadIdx.x & 31;
    if (g >= n_nodes) return;
    int beg = off[g], end = off[g + 1];
    float4 a0 = {0,0,0,0}, a1 = {0,0,0,0}, a2 = {0,0,0,0}, a3 = {0,0,0,0};
    const size_t lo = (size_t)(lane * 4);
    int i = beg;
    for (; i + 4 <= end; i += 4) {
        int s0 = elist[i], s1 = elist[i+1], s2 = elist[i+2], s3 = elist[i+3];
        float4 v0 = *(const float4*)(h + (size_t)s0 * HD + lo);
        float4 v1 = *(const float4*)(h + (size_t)s1 * HD + lo);
        float4 v2 = *(const float4*)(h + (size_t)s2 * HD + lo);
        float4 v3 = *(const float4*)(h + (size_t)s3 * HD + lo);
        a0.x += v0.x; a0.y += v0.y; a0.z += v0.z; a0.w += v0.w;
        a1.x += v1.x; a1.y += v1.y; a1.z += v1.z; a1.w += v1.w;
        a2.x += v2.x; a2.y += v2.y; a2.z += v2.z; a2.w += v2.w;
        a3.x += v3.x; a3.y += v3.y; a3.z += v3.z; a3.w += v3.w;
    }
    for (; i < end; ++i) {
        int s0 = elist[i];
        float4 v0 = *(const float4*)(h + (size_t)s0 * HD + lo);
        a0.x += v0.x; a0.y += v0.y; a0.z += v0.z; a0.w += v0.w;
    }
    float4 acc;
    acc.x = (a0.x + a1.x) + (a2.x + a3.x);
    acc.y = (a0.y + a1.y) + (a2.y + a3.y);
    acc.z = (a0.z + a1.z) + (a2.z + a3.z);
    acc.w = (a0.w + a1.w) + (a2.w + a3.w);
    *(float4*)(S + (size_t)g * HD + lo) = acc;
}

// ---------------- W repack: Wt[j][k] = bf16(W[k][j]), [128][256] ----------------

__global__ __launch_bounds__(256) void wt_convert(
    const float* __restrict__ W, short* __restrict__ Wt)
{
    int idx = blockIdx.x * 256 + threadIdx.x;
    int j = idx >> 8;
    int k = idx & 255;
    Wt[idx] = f2bf(W[k * HD + j]);
}

// ---------------- MFMA node kernel (col-split x2) ----------------
// Wave: 16 rows x 64 cols, K=256, 32x mfma_f32_16x16x32_bf16.
// A/B frags both use k = (lane>>4)*8 + slot (consistent k-bijection -> exact).
// C/D: col = lane&15, row = (lane>>4)*4 + reg  [HW-verified m89/m91].
__global__ __launch_bounds__(256) void mpnn_node_mfma(
    const float* __restrict__ h,
    const short* __restrict__ Wt,    // [128][256] bf16
    const float* __restrict__ bias,  // [128] f32
    const int* __restrict__ deg,
    float* __restrict__ S,           // in: scatter sums [N][128]; out: final
    int n_nodes)
{
    const int lane = threadIdx.x & 63;
    const int wv = threadIdx.x >> 6;          // 0..3
    const int m0 = blockIdx.x * 32 + (wv >> 1) * 16;
    const int c0 = (wv & 1) * 64;
    if (m0 >= n_nodes) return;
    const int row = lane & 15;
    const int g = lane >> 4;

    // ---- prefetch epilogue operands (fly under MFMAs) ----
    const int nBase = m0 + g * 4;
    float dgO[4], hv[4][4], bc[4];
    #pragma unroll
    for (int r = 0; r < 4; ++r) {
        int n = nBase + r;
        int nc = (n < n_nodes) ? n : (n_nodes - 1);
        dgO[r] = (float)deg[nc];
        #pragma unroll
        for (int jt = 0; jt < 4; ++jt)
            hv[jt][r] = h[(size_t)nc * HD + c0 + jt * 16 + row];
    }
    #pragma unroll
    for (int jt = 0; jt < 4; ++jt) bc[jt] = bias[c0 + jt * 16 + row];

    // ---- A fragments: rows of [S | deg*h] ----
    int mA = m0 + row;
    if (mA > n_nodes - 1) mA = n_nodes - 1;
    const float dgA = (float)deg[mA];

    bf16x8 a[8];
    #pragma unroll
    for (int kf = 0; kf < 4; ++kf) {             // k 0..127 : S
        const float4* p = (const float4*)(S + (size_t)mA * HD + kf * 32 + g * 8);
        float4 x = p[0], y = p[1];
        bf16x8 t = { f2bf(x.x), f2bf(x.y), f2bf(x.z), f2bf(x.w),
                     f2bf(y.x), f2bf(y.y), f2bf(y.z), f2bf(y.w) };
        a[kf] = t;
    }
    #pragma unroll
    for (int kf = 0; kf < 4; ++kf) {             // k 128..255 : deg*h
        const float4* p = (const float4*)(h + (size_t)mA * HD + kf * 32 + g * 8);
        float4 x = p[0], y = p[1];
        bf16x8 t = { f2bf(dgA * x.x), f2bf(dgA * x.y), f2bf(dgA * x.z), f2bf(dgA * x.w),
                     f2bf(dgA * y.x), f2bf(dgA * y.y), f2bf(dgA * y.z), f2bf(dgA * y.w) };
        a[4 + kf] = t;
    }

    f32x4 acc[4];
    #pragma unroll
    for (int jt = 0; jt < 4; ++jt) acc[jt] = (f32x4){0.f, 0.f, 0.f, 0.f};

    #pragma unroll
    for (int jt = 0; jt < 4; ++jt) {
        const short* wj = Wt + (size_t)(c0 + jt * 16 + row) * 256 + g * 8;
        #pragma unroll
        for (int kf = 0; kf < 8; ++kf) {
            bf16x8 bf = *(const bf16x8*)(wj + kf * 32);
            acc[jt] = __builtin_amdgcn_mfma_f32_16x16x32_bf16(a[kf], bf, acc[jt], 0, 0, 0);
        }
    }

    // ---- epilogue ----
    #pragma unroll
    for (int jt = 0; jt < 4; ++jt) {
        const int col = c0 + jt * 16 + row;
        #pragma unroll
        for (int r = 0; r < 4; ++r) {
            int n = nBase + r;
            if (n < n_nodes) {
                float agg = acc[jt][r] + dgO[r] * bc[jt];
                float out = fast_sigmoid(agg) + fast_softplus(hv[jt][r]);
                S[(size_t)n * HD + col] = out;
            }
        }
    }
}

// ---------------- fallback f32 node kernel (tiny-ws tier) ----------------

__global__ __launch_bounds__(256) void mpnn_node_f32(
    const float* __restrict__ h, const float* __restrict__ W,
    const float* __restrict__ b, const int* __restrict__ deg,
    float* __restrict__ S, int n_nodes)
{
    const int j = threadIdx.x & (HD - 1);
    const int g = threadIdx.x >> 7;
    const int n0 = blockIdx.x * NPB + g * RPT;

    float accS[RPT], accH[RPT];
    #pragma unroll
    for (int r = 0; r < RPT; ++r) { accS[r] = 0.f; accH[r] = 0.f; }

    int rmax = n_nodes - n0;
    if (rmax > RPT) rmax = RPT;
    if (rmax < 0) rmax = 0;

    for (int k = 0; k < HD; k += 4) {
        float w0 = W[(k + 0) * HD + j], w1 = W[(k + 1) * HD + j];
        float w2 = W[(k + 2) * HD + j], w3 = W[(k + 3) * HD + j];
        #pragma unroll
        for (int r = 0; r < RPT; ++r) if (r < rmax) {
            float4 a = *(const float4*)(S + (size_t)(n0 + r) * HD + k);
            accS[r] = fmaf(a.x, w0, fmaf(a.y, w1, fmaf(a.z, w2, fmaf(a.w, w3, accS[r]))));
        }
    }
    for (int k = 0; k < HD; k += 4) {
        float w0 = W[(HD + k + 0) * HD + j], w1 = W[(HD + k + 1) * HD + j];
        float w2 = W[(HD + k + 2) * HD + j], w3 = W[(HD + k + 3) * HD + j];
        #pragma unroll
        for (int r = 0; r < RPT; ++r) if (r < rmax) {
            float4 a = *(const float4*)(h + (size_t)(n0 + r) * HD + k);
            accH[r] = fmaf(a.x, w0, fmaf(a.y, w1, fmaf(a.z, w2, fmaf(a.w, w3, accH[r]))));
        }
    }
    __syncthreads();
    #pragma unroll
    for (int r = 0; r < RPT; ++r) if (r < rmax) {
        int n = n0 + r;
        float dg = (float)deg[n];
        float agg = accS[r] + dg * (accH[r] + b[j]);
        float hvv = h[(size_t)n * HD + j];
        S[(size_t)n * HD + j] = fast_sigmoid(agg) + fast_softplus(hvv);
    }
}

__global__ __launch_bounds__(256) void mpnn_scatter(
    const float* __restrict__ h, const int* __restrict__ src,
    const int* __restrict__ dst, float* __restrict__ S,
    int* __restrict__ deg, int n_edges)
{
    int gid = blockIdx.x * 256 + threadIdx.x;
    int e = gid >> 5;
    if (e >= n_edges) return;
    int lane = gid & 31;
    int s = src[e], d = dst[e];
    float4 v = *(const float4*)(h + (size_t)s * HD + lane * 4);
    float* srow = S + (size_t)d * HD + lane * 4;
    atomicAdd(srow + 0, v.x);
    atomicAdd(srow + 1, v.y);
    atomicAdd(srow + 2, v.z);
    atomicAdd(srow + 3, v.w);
    if (lane == 0) atomicAdd(deg + d, 1);
}

extern "C" void kernel_launch(void* const* d_in, const int* in_sizes, int n_in,
                              void* d_out, int out_size, void* d_ws, size_t ws_size,
                              hipStream_t stream)
{
    const float* h   = (const float*)d_in[0];
    const int*   src = (const int*)d_in[1];
    const int*   dst = (const int*)d_in[2];
    const float* W   = (const float*)d_in[3];
    const float* b   = (const float*)d_in[4];
    float* S = (float*)d_out;

    const int n_nodes = in_sizes[0] / HD;
    const int n_edges = in_sizes[1];
    const int WT_INTS = 2 * HD * HD / 2;   // 32768 shorts = 16384 ints

    const size_t need_full = ((size_t)3 * n_nodes + 1 + n_edges + WT_INTS) * sizeof(int);
    const size_t need_mid  = ((size_t)n_nodes + WT_INTS) * sizeof(int);
    const int mblocks = (n_nodes + 31) / 32;          // MFMA kernel: 32 rows/block

    if (ws_size >= need_full) {
        // CSR + MFMA
        int* deg   = (int*)d_ws;
        int* off   = deg + n_nodes;
        int* cur   = off + n_nodes + 1;
        int* elist = cur + n_nodes;
        short* Wt  = (short*)(elist + n_edges);

        hipMemsetAsync(deg, 0, (size_t)n_nodes * sizeof(int), stream);
        wt_convert<<<(2 * HD * HD) / 256, 256, 0, stream>>>(W, Wt);
        edge_hist<<<(n_edges + 255) / 256, 256, 0, stream>>>(dst, deg, n_edges);
        scan_deg<<<1, 1024, 0, stream>>>(deg, off, cur, n_nodes, n_edges);
        edge_fill<<<(n_edges + 255) / 256, 256, 0, stream>>>(src, dst, cur, elist, n_edges);

        const int gblocks = (int)(((long long)n_nodes * 32 + 255) / 256);
        node_gather<<<gblocks, 256, 0, stream>>>(h, off, elist, S, n_nodes);

        mpnn_node_mfma<<<mblocks, 256, 0, stream>>>(h, Wt, b, deg, S, n_nodes);
    } else if (ws_size >= need_mid) {
        // atomic scatter + MFMA
        int* deg  = (int*)d_ws;
        short* Wt = (short*)(deg + n_nodes);
        hipMemsetAsync(d_out, 0, (size_t)n_nodes * HD * sizeof(float), stream);
        hipMemsetAsync(deg, 0, (size_t)n_nodes * sizeof(int), stream);
        wt_convert<<<(2 * HD * HD) / 256, 256, 0, stream>>>(W, Wt);
        const int sblocks = (int)(((long long)n_edges * 32 + 255) / 256);
        mpnn_scatter<<<sblocks, 256, 0, stream>>>(h, src, dst, S, deg, n_edges);
        mpnn_node_mfma<<<mblocks, 256, 0, stream>>>(h, Wt, b, deg, S, n_nodes);
    } else {
        // minimal ws: atomic scatter + f32 node
        int* deg = (int*)d_ws;
        hipMemsetAsync(d_out, 0, (size_t)n_nodes * HD * sizeof(float), stream);
        hipMemsetAsync(deg, 0, (size_t)n_nodes * sizeof(int), stream);
        const int sblocks = (int)(((long long)n_edges * 32 + 255) / 256);
        mpnn_scatter<<<sblocks, 256, 0, stream>>>(h, src, dst, S, deg, n_edges);
        const int nblocks = (n_nodes + NPB - 1) / NPB;
        mpnn_node_f32<<<nblocks, 256, 0, stream>>>(h, W, b, deg, S, n_nodes);
    }
}

// Round 6
// 169.289 us; speedup vs baseline: 8.1515x; 1.2535x over previous
//
#include <hip/hip_runtime.h>
#include <math.h>

#define HD 128
#define NPB 16
#define RPT 8

typedef __attribute__((ext_vector_type(8))) short bf16x8;
typedef __attribute__((ext_vector_type(4))) float f32x4;

__device__ inline short f2bf(float x) {   // RTNE f32->bf16
    union { float f; unsigned u; } v; v.f = x;
    unsigned r = v.u + 0x7fff + ((v.u >> 16) & 1);
    return (short)(r >> 16);
}

#define LOG2E 1.4426950408889634f
#define LN2   0.6931471805599453f

__device__ inline float fast_sigmoid(float x) {
    return __builtin_amdgcn_rcpf(1.0f + __builtin_amdgcn_exp2f(-LOG2E * x));
}
__device__ inline float fast_softplus(float x) {
    float t = __builtin_amdgcn_exp2f(-LOG2E * fabsf(x));
    return fmaxf(x, 0.0f) + LN2 * __builtin_amdgcn_logf(1.0f + t);
}

// ---------------- CSR build ----------------

__global__ __launch_bounds__(256) void edge_hist(
    const int* __restrict__ dst, int* __restrict__ deg, int n_edges)
{
    int e = blockIdx.x * 256 + threadIdx.x;
    if (e < n_edges) atomicAdd(&deg[dst[e]], 1);
}

// hierarchical scan, step 1: block-local exclusive scan + block totals
__global__ __launch_bounds__(1024) void scan_blocks(
    const int* __restrict__ deg, int* __restrict__ off,
    int* __restrict__ bsum, int n_nodes)
{
    __shared__ int wtot[16];
    const int t = threadIdx.x;
    const int lane = t & 63;
    const int wid = t >> 6;
    int idx = blockIdx.x * 1024 + t;
    int v = (idx < n_nodes) ? deg[idx] : 0;
    int incl = v;
    #pragma unroll
    for (int o = 1; o < 64; o <<= 1) {
        int y = __shfl_up(incl, o, 64);
        if (lane >= o) incl += y;
    }
    if (lane == 63) wtot[wid] = incl;
    __syncthreads();
    if (wid == 0) {
        int w = (lane < 16) ? wtot[lane] : 0;
        int wi = w;
        #pragma unroll
        for (int o = 1; o < 16; o <<= 1) {
            int y = __shfl_up(wi, o, 64);
            if (lane >= o) wi += y;
        }
        if (lane < 16) wtot[lane] = wi - w;    // exclusive wave offsets
    }
    __syncthreads();
    int excl = wtot[wid] + incl - v;
    if (idx < n_nodes) off[idx] = excl;        // block-local exclusive
    if (t == 1023) bsum[blockIdx.x] = wtot[15] + incl;   // block total
}

// step 2: exclusive scan of block totals (single wave, loop with carry)
__global__ __launch_bounds__(64) void scan_partials(int* __restrict__ bsum, int nb)
{
    const int lane = threadIdx.x;
    int carry = 0;
    for (int base = 0; base < nb; base += 64) {
        int i = base + lane;
        int v = (i < nb) ? bsum[i] : 0;
        int incl = v;
        #pragma unroll
        for (int o = 1; o < 64; o <<= 1) {
            int y = __shfl_up(incl, o, 64);
            if (lane >= o) incl += y;
        }
        if (i < nb) bsum[i] = carry + incl - v;
        carry += __shfl(incl, 63, 64);
    }
}

// step 3: add block offsets, produce off + cur
__global__ __launch_bounds__(1024) void scan_apply(
    int* __restrict__ off, int* __restrict__ cur,
    const int* __restrict__ bsum, int n_nodes, int n_edges)
{
    int idx = blockIdx.x * 1024 + threadIdx.x;
    if (idx < n_nodes) {
        int v = off[idx] + bsum[blockIdx.x];
        off[idx] = v;
        cur[idx] = v;
    }
    if (idx == 0) off[n_nodes] = n_edges;
}

__global__ __launch_bounds__(256) void edge_fill(
    const int* __restrict__ src, const int* __restrict__ dst,
    int* __restrict__ cur, int* __restrict__ elist, int n_edges)
{
    int e = blockIdx.x * 256 + threadIdx.x;
    if (e < n_edges) {
        int d = dst[e];
        int pos = atomicAdd(&cur[d], 1);
        elist[pos] = src[e];
    }
}

// ------- gather-sum: S[n] = sum_{e: dst[e]=n} h[src[e]], 4 independent chains -------

__global__ __launch_bounds__(256) void node_gather(
    const float* __restrict__ h, const int* __restrict__ off,
    const int* __restrict__ elist, float* __restrict__ S, int n_nodes)
{
    int g = (blockIdx.x * 256 + threadIdx.x) >> 5;
    int lane = threadIdx.x & 31;
    if (g >= n_nodes) return;
    int beg = off[g], end = off[g + 1];
    float4 a0 = {0,0,0,0}, a1 = {0,0,0,0}, a2 = {0,0,0,0}, a3 = {0,0,0,0};
    const size_t lo = (size_t)(lane * 4);
    int i = beg;
    for (; i + 4 <= end; i += 4) {
        int s0 = elist[i], s1 = elist[i+1], s2 = elist[i+2], s3 = elist[i+3];
        float4 v0 = *(const float4*)(h + (size_t)s0 * HD + lo);
        float4 v1 = *(const float4*)(h + (size_t)s1 * HD + lo);
        float4 v2 = *(const float4*)(h + (size_t)s2 * HD + lo);
        float4 v3 = *(const float4*)(h + (size_t)s3 * HD + lo);
        a0.x += v0.x; a0.y += v0.y; a0.z += v0.z; a0.w += v0.w;
        a1.x += v1.x; a1.y += v1.y; a1.z += v1.z; a1.w += v1.w;
        a2.x += v2.x; a2.y += v2.y; a2.z += v2.z; a2.w += v2.w;
        a3.x += v3.x; a3.y += v3.y; a3.z += v3.z; a3.w += v3.w;
    }
    for (; i < end; ++i) {
        int s0 = elist[i];
        float4 v0 = *(const float4*)(h + (size_t)s0 * HD + lo);
        a0.x += v0.x; a0.y += v0.y; a0.z += v0.z; a0.w += v0.w;
    }
    float4 acc;
    acc.x = (a0.x + a1.x) + (a2.x + a3.x);
    acc.y = (a0.y + a1.y) + (a2.y + a3.y);
    acc.z = (a0.z + a1.z) + (a2.z + a3.z);
    acc.w = (a0.w + a1.w) + (a2.w + a3.w);
    *(float4*)(S + (size_t)g * HD + lo) = acc;
}

// ---------------- W repack: Wt[j][k] = bf16(W[k][j]), [128][256] ----------------

__global__ __launch_bounds__(256) void wt_convert(
    const float* __restrict__ W, short* __restrict__ Wt)
{
    int idx = blockIdx.x * 256 + threadIdx.x;
    int j = idx >> 8;
    int k = idx & 255;
    Wt[idx] = f2bf(W[k * HD + j]);
}

// ---------------- MFMA node kernel (col-split x2) ----------------
__global__ __launch_bounds__(256) void mpnn_node_mfma(
    const float* __restrict__ h,
    const short* __restrict__ Wt,    // [128][256] bf16
    const float* __restrict__ bias,  // [128] f32
    const int* __restrict__ deg,
    float* __restrict__ S,           // in: scatter sums [N][128]; out: final
    int n_nodes)
{
    const int lane = threadIdx.x & 63;
    const int wv = threadIdx.x >> 6;          // 0..3
    const int m0 = blockIdx.x * 32 + (wv >> 1) * 16;
    const int c0 = (wv & 1) * 64;
    if (m0 >= n_nodes) return;
    const int row = lane & 15;
    const int g = lane >> 4;

    // prefetch epilogue operands
    const int nBase = m0 + g * 4;
    float dgO[4], hv[4][4], bc[4];
    #pragma unroll
    for (int r = 0; r < 4; ++r) {
        int n = nBase + r;
        int nc = (n < n_nodes) ? n : (n_nodes - 1);
        dgO[r] = (float)deg[nc];
        #pragma unroll
        for (int jt = 0; jt < 4; ++jt)
            hv[jt][r] = h[(size_t)nc * HD + c0 + jt * 16 + row];
    }
    #pragma unroll
    for (int jt = 0; jt < 4; ++jt) bc[jt] = bias[c0 + jt * 16 + row];

    // A fragments: rows of [S | deg*h]
    int mA = m0 + row;
    if (mA > n_nodes - 1) mA = n_nodes - 1;
    const float dgA = (float)deg[mA];

    bf16x8 a[8];
    #pragma unroll
    for (int kf = 0; kf < 4; ++kf) {             // k 0..127 : S
        const float4* p = (const float4*)(S + (size_t)mA * HD + kf * 32 + g * 8);
        float4 x = p[0], y = p[1];
        bf16x8 t = { f2bf(x.x), f2bf(x.y), f2bf(x.z), f2bf(x.w),
                     f2bf(y.x), f2bf(y.y), f2bf(y.z), f2bf(y.w) };
        a[kf] = t;
    }
    #pragma unroll
    for (int kf = 0; kf < 4; ++kf) {             // k 128..255 : deg*h
        const float4* p = (const float4*)(h + (size_t)mA * HD + kf * 32 + g * 8);
        float4 x = p[0], y = p[1];
        bf16x8 t = { f2bf(dgA * x.x), f2bf(dgA * x.y), f2bf(dgA * x.z), f2bf(dgA * x.w),
                     f2bf(dgA * y.x), f2bf(dgA * y.y), f2bf(dgA * y.z), f2bf(dgA * y.w) };
        a[4 + kf] = t;
    }

    f32x4 acc[4];
    #pragma unroll
    for (int jt = 0; jt < 4; ++jt) acc[jt] = (f32x4){0.f, 0.f, 0.f, 0.f};

    #pragma unroll
    for (int jt = 0; jt < 4; ++jt) {
        const short* wj = Wt + (size_t)(c0 + jt * 16 + row) * 256 + g * 8;
        #pragma unroll
        for (int kf = 0; kf < 8; ++kf) {
            bf16x8 bf = *(const bf16x8*)(wj + kf * 32);
            acc[jt] = __builtin_amdgcn_mfma_f32_16x16x32_bf16(a[kf], bf, acc[jt], 0, 0, 0);
        }
    }

    // epilogue
    #pragma unroll
    for (int jt = 0; jt < 4; ++jt) {
        const int col = c0 + jt * 16 + row;
        #pragma unroll
        for (int r = 0; r < 4; ++r) {
            int n = nBase + r;
            if (n < n_nodes) {
                float agg = acc[jt][r] + dgO[r] * bc[jt];
                S[(size_t)n * HD + col] = fast_sigmoid(agg) + fast_softplus(hv[jt][r]);
            }
        }
    }
}

// ---------------- fallback f32 node kernel (tiny-ws tier) ----------------

__global__ __launch_bounds__(256) void mpnn_node_f32(
    const float* __restrict__ h, const float* __restrict__ W,
    const float* __restrict__ b, const int* __restrict__ deg,
    float* __restrict__ S, int n_nodes)
{
    const int j = threadIdx.x & (HD - 1);
    const int g = threadIdx.x >> 7;
    const int n0 = blockIdx.x * NPB + g * RPT;

    float accS[RPT], accH[RPT];
    #pragma unroll
    for (int r = 0; r < RPT; ++r) { accS[r] = 0.f; accH[r] = 0.f; }

    int rmax = n_nodes - n0;
    if (rmax > RPT) rmax = RPT;
    if (rmax < 0) rmax = 0;

    for (int k = 0; k < HD; k += 4) {
        float w0 = W[(k + 0) * HD + j], w1 = W[(k + 1) * HD + j];
        float w2 = W[(k + 2) * HD + j], w3 = W[(k + 3) * HD + j];
        #pragma unroll
        for (int r = 0; r < RPT; ++r) if (r < rmax) {
            float4 a = *(const float4*)(S + (size_t)(n0 + r) * HD + k);
            accS[r] = fmaf(a.x, w0, fmaf(a.y, w1, fmaf(a.z, w2, fmaf(a.w, w3, accS[r]))));
        }
    }
    for (int k = 0; k < HD; k += 4) {
        float w0 = W[(HD + k + 0) * HD + j], w1 = W[(HD + k + 1) * HD + j];
        float w2 = W[(HD + k + 2) * HD + j], w3 = W[(HD + k + 3) * HD + j];
        #pragma unroll
        for (int r = 0; r < RPT; ++r) if (r < rmax) {
            float4 a = *(const float4*)(h + (size_t)(n0 + r) * HD + k);
            accH[r] = fmaf(a.x, w0, fmaf(a.y, w1, fmaf(a.z, w2, fmaf(a.w, w3, accH[r]))));
        }
    }
    __syncthreads();
    #pragma unroll
    for (int r = 0; r < RPT; ++r) if (r < rmax) {
        int n = n0 + r;
        float dg = (float)deg[n];
        float agg = accS[r] + dg * (accH[r] + b[j]);
        float hvv = h[(size_t)n * HD + j];
        S[(size_t)n * HD + j] = fast_sigmoid(agg) + fast_softplus(hvv);
    }
}

__global__ __launch_bounds__(256) void mpnn_scatter(
    const float* __restrict__ h, const int* __restrict__ src,
    const int* __restrict__ dst, float* __restrict__ S,
    int* __restrict__ deg, int n_edges)
{
    int gid = blockIdx.x * 256 + threadIdx.x;
    int e = gid >> 5;
    if (e >= n_edges) return;
    int lane = gid & 31;
    int s = src[e], d = dst[e];
    float4 v = *(const float4*)(h + (size_t)s * HD + lane * 4);
    float* srow = S + (size_t)d * HD + lane * 4;
    atomicAdd(srow + 0, v.x);
    atomicAdd(srow + 1, v.y);
    atomicAdd(srow + 2, v.z);
    atomicAdd(srow + 3, v.w);
    if (lane == 0) atomicAdd(deg + d, 1);
}

extern "C" void kernel_launch(void* const* d_in, const int* in_sizes, int n_in,
                              void* d_out, int out_size, void* d_ws, size_t ws_size,
                              hipStream_t stream)
{
    const float* h   = (const float*)d_in[0];
    const int*   src = (const int*)d_in[1];
    const int*   dst = (const int*)d_in[2];
    const float* W   = (const float*)d_in[3];
    const float* b   = (const float*)d_in[4];
    float* S = (float*)d_out;

    const int n_nodes = in_sizes[0] / HD;
    const int n_edges = in_sizes[1];
    const int WT_INTS = 2 * HD * HD / 2;            // 32768 shorts = 16384 ints
    const int nb = (n_nodes + 1023) / 1024;         // scan blocks

    const size_t need_full = ((size_t)3 * n_nodes + 1 + n_edges + WT_INTS + nb) * sizeof(int);
    const size_t need_mid  = ((size_t)n_nodes + WT_INTS) * sizeof(int);
    const int mblocks = (n_nodes + 31) / 32;        // MFMA kernel: 32 rows/block

    if (ws_size >= need_full) {
        // CSR + MFMA
        int* deg   = (int*)d_ws;
        int* off   = deg + n_nodes;                 // n_nodes + 1
        int* cur   = off + n_nodes + 1;             // n_nodes
        int* elist = cur + n_nodes;                 // n_edges
        short* Wt  = (short*)(elist + n_edges);     // 32768 shorts
        int* bsum  = (int*)(Wt + 2 * HD * HD);      // nb

        hipMemsetAsync(deg, 0, (size_t)n_nodes * sizeof(int), stream);
        wt_convert<<<(2 * HD * HD) / 256, 256, 0, stream>>>(W, Wt);
        edge_hist<<<(n_edges + 255) / 256, 256, 0, stream>>>(dst, deg, n_edges);

        scan_blocks<<<nb, 1024, 0, stream>>>(deg, off, bsum, n_nodes);
        scan_partials<<<1, 64, 0, stream>>>(bsum, nb);
        scan_apply<<<nb, 1024, 0, stream>>>(off, cur, bsum, n_nodes, n_edges);

        edge_fill<<<(n_edges + 255) / 256, 256, 0, stream>>>(src, dst, cur, elist, n_edges);

        const int gblocks = (int)(((long long)n_nodes * 32 + 255) / 256);
        node_gather<<<gblocks, 256, 0, stream>>>(h, off, elist, S, n_nodes);

        mpnn_node_mfma<<<mblocks, 256, 0, stream>>>(h, Wt, b, deg, S, n_nodes);
    } else if (ws_size >= need_mid) {
        // atomic scatter + MFMA
        int* deg  = (int*)d_ws;
        short* Wt = (short*)(deg + n_nodes);
        hipMemsetAsync(d_out, 0, (size_t)n_nodes * HD * sizeof(float), stream);
        hipMemsetAsync(deg, 0, (size_t)n_nodes * sizeof(int), stream);
        wt_convert<<<(2 * HD * HD) / 256, 256, 0, stream>>>(W, Wt);
        const int sblocks = (int)(((long long)n_edges * 32 + 255) / 256);
        mpnn_scatter<<<sblocks, 256, 0, stream>>>(h, src, dst, S, deg, n_edges);
        mpnn_node_mfma<<<mblocks, 256, 0, stream>>>(h, Wt, b, deg, S, n_nodes);
    } else {
        // minimal ws: atomic scatter + f32 node
        int* deg = (int*)d_ws;
        hipMemsetAsync(d_out, 0, (size_t)n_nodes * HD * sizeof(float), stream);
        hipMemsetAsync(deg, 0, (size_t)n_nodes * sizeof(int), stream);
        const int sblocks = (int)(((long long)n_edges * 32 + 255) / 256);
        mpnn_scatter<<<sblocks, 256, 0, stream>>>(h, src, dst, S, deg, n_edges);
        const int nblocks = (n_nodes + NPB - 1) / NPB;
        mpnn_node_f32<<<nblocks, 256, 0, stream>>>(h, W, b, deg, S, n_nodes);
    }
}

// Round 7
// 151.129 us; speedup vs baseline: 9.1310x; 1.1202x over previous
//
#include <hip/hip_runtime.h>
#include <math.h>

#define HD 128
#define NPB 16
#define RPT 8

typedef __attribute__((ext_vector_type(8))) short bf16x8;
typedef __attribute__((ext_vector_type(4))) float f32x4;

__device__ inline short f2bf(float x) {   // RTNE f32->bf16
    union { float f; unsigned u; } v; v.f = x;
    unsigned r = v.u + 0x7fff + ((v.u >> 16) & 1);
    return (short)(r >> 16);
}
__device__ inline float bf2f(short x) {
    union { unsigned u; float f; } v;
    v.u = ((unsigned)(unsigned short)x) << 16;
    return v.f;
}

#define LOG2E 1.4426950408889634f
#define LN2   0.6931471805599453f

__device__ inline float fast_sigmoid(float x) {
    return __builtin_amdgcn_rcpf(1.0f + __builtin_amdgcn_exp2f(-LOG2E * x));
}
__device__ inline float fast_softplus(float x) {
    float t = __builtin_amdgcn_exp2f(-LOG2E * fabsf(x));
    return fmaxf(x, 0.0f) + LN2 * __builtin_amdgcn_logf(1.0f + t);
}

// ---------- fused prep: Wt repack + h->bf16 + degree histogram ----------

__global__ __launch_bounds__(256) void prep(
    const float* __restrict__ W, short* __restrict__ Wt,
    const float* __restrict__ h, short* __restrict__ hb,
    const int* __restrict__ dst, int* __restrict__ deg,
    int n_nodes, int n_edges)
{
    const int tid = blockIdx.x * 256 + threadIdx.x;
    const int total = gridDim.x * 256;

    // h -> bf16, 8 elems/thread
    const int hitems = n_nodes * HD / 8;
    for (int i = tid; i < hitems; i += total) {
        const float4* p = (const float4*)(h + (size_t)i * 8);
        float4 x = p[0], y = p[1];
        bf16x8 t = { f2bf(x.x), f2bf(x.y), f2bf(x.z), f2bf(x.w),
                     f2bf(y.x), f2bf(y.y), f2bf(y.z), f2bf(y.w) };
        *(bf16x8*)(hb + (size_t)i * 8) = t;
    }
    // Wt[j][k] = bf16(W[k][j])
    for (int i = tid; i < 2 * HD * HD; i += total) {
        int j = i >> 8, k = i & 255;
        Wt[i] = f2bf(W[k * HD + j]);
    }
    // degree histogram
    for (int e = tid; e < n_edges; e += total)
        atomicAdd(&deg[dst[e]], 1);
}

// ---------------- hierarchical scan ----------------

__global__ __launch_bounds__(1024) void scan_blocks(
    const int* __restrict__ deg, int* __restrict__ off,
    int* __restrict__ bsum, int n_nodes)
{
    __shared__ int wtot[16];
    const int t = threadIdx.x;
    const int lane = t & 63;
    const int wid = t >> 6;
    int idx = blockIdx.x * 1024 + t;
    int v = (idx < n_nodes) ? deg[idx] : 0;
    int incl = v;
    #pragma unroll
    for (int o = 1; o < 64; o <<= 1) {
        int y = __shfl_up(incl, o, 64);
        if (lane >= o) incl += y;
    }
    if (lane == 63) wtot[wid] = incl;
    __syncthreads();
    if (wid == 0) {
        int w = (lane < 16) ? wtot[lane] : 0;
        int wi = w;
        #pragma unroll
        for (int o = 1; o < 16; o <<= 1) {
            int y = __shfl_up(wi, o, 64);
            if (lane >= o) wi += y;
        }
        if (lane < 16) wtot[lane] = wi - w;
    }
    __syncthreads();
    int excl = wtot[wid] + incl - v;
    if (idx < n_nodes) off[idx] = excl;
    if (t == 1023) bsum[blockIdx.x] = wtot[15] + incl;
}

__global__ __launch_bounds__(64) void scan_partials(int* __restrict__ bsum, int nb)
{
    const int lane = threadIdx.x;
    int carry = 0;
    for (int base = 0; base < nb; base += 64) {
        int i = base + lane;
        int v = (i < nb) ? bsum[i] : 0;
        int incl = v;
        #pragma unroll
        for (int o = 1; o < 64; o <<= 1) {
            int y = __shfl_up(incl, o, 64);
            if (lane >= o) incl += y;
        }
        if (i < nb) bsum[i] = carry + incl - v;
        carry += __shfl(incl, 63, 64);
    }
}

__global__ __launch_bounds__(1024) void scan_apply(
    int* __restrict__ off, int* __restrict__ cur,
    const int* __restrict__ bsum, int n_nodes, int n_edges)
{
    int idx = blockIdx.x * 1024 + threadIdx.x;
    if (idx < n_nodes) {
        int v = off[idx] + bsum[blockIdx.x];
        off[idx] = v;
        cur[idx] = v;
    }
    if (idx == 0) off[n_nodes] = n_edges;
}

__global__ __launch_bounds__(256) void edge_fill(
    const int* __restrict__ src, const int* __restrict__ dst,
    int* __restrict__ cur, int* __restrict__ elist, int n_edges)
{
    int e = blockIdx.x * 256 + threadIdx.x;
    if (e < n_edges) {
        int d = dst[e];
        int pos = atomicAdd(&cur[d], 1);
        elist[pos] = src[e];
    }
}

// ------- bf16 gather-sum: Sb[n] = bf16( sum_{e: dst[e]=n} hb[src[e]] ) -------
// 16 lanes/node, each lane owns 8 cols (16B loads), f32 accumulate, one RTNE round.

__global__ __launch_bounds__(256) void node_gather_bf16(
    const short* __restrict__ hb, const int* __restrict__ off,
    const int* __restrict__ elist, short* __restrict__ Sb, int n_nodes)
{
    int g = (blockIdx.x * 256 + threadIdx.x) >> 4;   // node
    int lane = threadIdx.x & 15;
    if (g >= n_nodes) return;
    int beg = off[g], end = off[g + 1];
    const size_t lo = (size_t)(lane * 8);

    float a0[8], a1[8];
    #pragma unroll
    for (int q = 0; q < 8; ++q) { a0[q] = 0.f; a1[q] = 0.f; }

    int i = beg;
    for (; i + 4 <= end; i += 4) {
        int s0 = elist[i], s1 = elist[i+1], s2 = elist[i+2], s3 = elist[i+3];
        bf16x8 v0 = *(const bf16x8*)(hb + (size_t)s0 * HD + lo);
        bf16x8 v1 = *(const bf16x8*)(hb + (size_t)s1 * HD + lo);
        bf16x8 v2 = *(const bf16x8*)(hb + (size_t)s2 * HD + lo);
        bf16x8 v3 = *(const bf16x8*)(hb + (size_t)s3 * HD + lo);
        #pragma unroll
        for (int q = 0; q < 8; ++q) {
            a0[q] += bf2f(v0[q]) + bf2f(v2[q]);
            a1[q] += bf2f(v1[q]) + bf2f(v3[q]);
        }
    }
    for (; i < end; ++i) {
        int s0 = elist[i];
        bf16x8 v0 = *(const bf16x8*)(hb + (size_t)s0 * HD + lo);
        #pragma unroll
        for (int q = 0; q < 8; ++q) a0[q] += bf2f(v0[q]);
    }
    bf16x8 out;
    #pragma unroll
    for (int q = 0; q < 8; ++q) out[q] = f2bf(a0[q] + a1[q]);
    *(bf16x8*)(Sb + (size_t)g * HD + lo) = out;
}

// ---------------- MFMA node kernel, bf16-S variant (col-split x2) ----------------
// A/B frags both use k = (lane>>4)*8 + slot (consistent k-bijection -> exact).
// C/D: col = lane&15, row = (lane>>4)*4 + reg  [HW-verified m89/m91].
__global__ __launch_bounds__(256) void mpnn_node_mfma_sb(
    const float* __restrict__ h,
    const short* __restrict__ Sb,    // [N][128] bf16 scatter sums
    const short* __restrict__ Wt,    // [128][256] bf16
    const float* __restrict__ bias,  // [128] f32
    const int* __restrict__ deg,
    float* __restrict__ out,         // [N][128] f32 final
    int n_nodes)
{
    const int lane = threadIdx.x & 63;
    const int wv = threadIdx.x >> 6;          // 0..3
    const int m0 = blockIdx.x * 32 + (wv >> 1) * 16;
    const int c0 = (wv & 1) * 64;
    if (m0 >= n_nodes) return;
    const int row = lane & 15;
    const int g = lane >> 4;

    // prefetch epilogue operands
    const int nBase = m0 + g * 4;
    float dgO[4], hv[4][4], bc[4];
    #pragma unroll
    for (int r = 0; r < 4; ++r) {
        int n = nBase + r;
        int nc = (n < n_nodes) ? n : (n_nodes - 1);
        dgO[r] = (float)deg[nc];
        #pragma unroll
        for (int jt = 0; jt < 4; ++jt)
            hv[jt][r] = h[(size_t)nc * HD + c0 + jt * 16 + row];
    }
    #pragma unroll
    for (int jt = 0; jt < 4; ++jt) bc[jt] = bias[c0 + jt * 16 + row];

    // A fragments: rows of [Sb | deg*h]
    int mA = m0 + row;
    if (mA > n_nodes - 1) mA = n_nodes - 1;
    const float dgA = (float)deg[mA];

    bf16x8 a[8];
    #pragma unroll
    for (int kf = 0; kf < 4; ++kf)               // k 0..127 : Sb (direct bf16)
        a[kf] = *(const bf16x8*)(Sb + (size_t)mA * HD + kf * 32 + g * 8);
    #pragma unroll
    for (int kf = 0; kf < 4; ++kf) {             // k 128..255 : deg*h
        const float4* p = (const float4*)(h + (size_t)mA * HD + kf * 32 + g * 8);
        float4 x = p[0], y = p[1];
        bf16x8 t = { f2bf(dgA * x.x), f2bf(dgA * x.y), f2bf(dgA * x.z), f2bf(dgA * x.w),
                     f2bf(dgA * y.x), f2bf(dgA * y.y), f2bf(dgA * y.z), f2bf(dgA * y.w) };
        a[4 + kf] = t;
    }

    f32x4 acc[4];
    #pragma unroll
    for (int jt = 0; jt < 4; ++jt) acc[jt] = (f32x4){0.f, 0.f, 0.f, 0.f};

    #pragma unroll
    for (int jt = 0; jt < 4; ++jt) {
        const short* wj = Wt + (size_t)(c0 + jt * 16 + row) * 256 + g * 8;
        #pragma unroll
        for (int kf = 0; kf < 8; ++kf) {
            bf16x8 bf = *(const bf16x8*)(wj + kf * 32);
            acc[jt] = __builtin_amdgcn_mfma_f32_16x16x32_bf16(a[kf], bf, acc[jt], 0, 0, 0);
        }
    }

    #pragma unroll
    for (int jt = 0; jt < 4; ++jt) {
        const int col = c0 + jt * 16 + row;
        #pragma unroll
        for (int r = 0; r < 4; ++r) {
            int n = nBase + r;
            if (n < n_nodes) {
                float agg = acc[jt][r] + dgO[r] * bc[jt];
                out[(size_t)n * HD + col] = fast_sigmoid(agg) + fast_softplus(hv[jt][r]);
            }
        }
    }
}

// ================== fallback tiers (proven R6 path) ==================

__global__ __launch_bounds__(256) void edge_hist(
    const int* __restrict__ dst, int* __restrict__ deg, int n_edges)
{
    int e = blockIdx.x * 256 + threadIdx.x;
    if (e < n_edges) atomicAdd(&deg[dst[e]], 1);
}

__global__ __launch_bounds__(256) void wt_convert(
    const float* __restrict__ W, short* __restrict__ Wt)
{
    int idx = blockIdx.x * 256 + threadIdx.x;
    int j = idx >> 8;
    int k = idx & 255;
    Wt[idx] = f2bf(W[k * HD + j]);
}

__global__ __launch_bounds__(256) void node_gather(
    const float* __restrict__ h, const int* __restrict__ off,
    const int* __restrict__ elist, float* __restrict__ S, int n_nodes)
{
    int g = (blockIdx.x * 256 + threadIdx.x) >> 5;
    int lane = threadIdx.x & 31;
    if (g >= n_nodes) return;
    int beg = off[g], end = off[g + 1];
    float4 a0 = {0,0,0,0}, a1 = {0,0,0,0}, a2 = {0,0,0,0}, a3 = {0,0,0,0};
    const size_t lo = (size_t)(lane * 4);
    int i = beg;
    for (; i + 4 <= end; i += 4) {
        int s0 = elist[i], s1 = elist[i+1], s2 = elist[i+2], s3 = elist[i+3];
        float4 v0 = *(const float4*)(h + (size_t)s0 * HD + lo);
        float4 v1 = *(const float4*)(h + (size_t)s1 * HD + lo);
        float4 v2 = *(const float4*)(h + (size_t)s2 * HD + lo);
        float4 v3 = *(const float4*)(h + (size_t)s3 * HD + lo);
        a0.x += v0.x; a0.y += v0.y; a0.z += v0.z; a0.w += v0.w;
        a1.x += v1.x; a1.y += v1.y; a1.z += v1.z; a1.w += v1.w;
        a2.x += v2.x; a2.y += v2.y; a2.z += v2.z; a2.w += v2.w;
        a3.x += v3.x; a3.y += v3.y; a3.z += v3.z; a3.w += v3.w;
    }
    for (; i < end; ++i) {
        int s0 = elist[i];
        float4 v0 = *(const float4*)(h + (size_t)s0 * HD + lo);
        a0.x += v0.x; a0.y += v0.y; a0.z += v0.z; a0.w += v0.w;
    }
    float4 acc;
    acc.x = (a0.x + a1.x) + (a2.x + a3.x);
    acc.y = (a0.y + a1.y) + (a2.y + a3.y);
    acc.z = (a0.z + a1.z) + (a2.z + a3.z);
    acc.w = (a0.w + a1.w) + (a2.w + a3.w);
    *(float4*)(S + (size_t)g * HD + lo) = acc;
}

__global__ __launch_bounds__(256) void mpnn_node_mfma(
    const float* __restrict__ h,
    const short* __restrict__ Wt,
    const float* __restrict__ bias,
    const int* __restrict__ deg,
    float* __restrict__ S,
    int n_nodes)
{
    const int lane = threadIdx.x & 63;
    const int wv = threadIdx.x >> 6;
    const int m0 = blockIdx.x * 32 + (wv >> 1) * 16;
    const int c0 = (wv & 1) * 64;
    if (m0 >= n_nodes) return;
    const int row = lane & 15;
    const int g = lane >> 4;

    const int nBase = m0 + g * 4;
    float dgO[4], hv[4][4], bc[4];
    #pragma unroll
    for (int r = 0; r < 4; ++r) {
        int n = nBase + r;
        int nc = (n < n_nodes) ? n : (n_nodes - 1);
        dgO[r] = (float)deg[nc];
        #pragma unroll
        for (int jt = 0; jt < 4; ++jt)
            hv[jt][r] = h[(size_t)nc * HD + c0 + jt * 16 + row];
    }
    #pragma unroll
    for (int jt = 0; jt < 4; ++jt) bc[jt] = bias[c0 + jt * 16 + row];

    int mA = m0 + row;
    if (mA > n_nodes - 1) mA = n_nodes - 1;
    const float dgA = (float)deg[mA];

    bf16x8 a[8];
    #pragma unroll
    for (int kf = 0; kf < 4; ++kf) {
        const float4* p = (const float4*)(S + (size_t)mA * HD + kf * 32 + g * 8);
        float4 x = p[0], y = p[1];
        bf16x8 t = { f2bf(x.x), f2bf(x.y), f2bf(x.z), f2bf(x.w),
                     f2bf(y.x), f2bf(y.y), f2bf(y.z), f2bf(y.w) };
        a[kf] = t;
    }
    #pragma unroll
    for (int kf = 0; kf < 4; ++kf) {
        const float4* p = (const float4*)(h + (size_t)mA * HD + kf * 32 + g * 8);
        float4 x = p[0], y = p[1];
        bf16x8 t = { f2bf(dgA * x.x), f2bf(dgA * x.y), f2bf(dgA * x.z), f2bf(dgA * x.w),
                     f2bf(dgA * y.x), f2bf(dgA * y.y), f2bf(dgA * y.z), f2bf(dgA * y.w) };
        a[4 + kf] = t;
    }

    f32x4 acc[4];
    #pragma unroll
    for (int jt = 0; jt < 4; ++jt) acc[jt] = (f32x4){0.f, 0.f, 0.f, 0.f};

    #pragma unroll
    for (int jt = 0; jt < 4; ++jt) {
        const short* wj = Wt + (size_t)(c0 + jt * 16 + row) * 256 + g * 8;
        #pragma unroll
        for (int kf = 0; kf < 8; ++kf) {
            bf16x8 bf = *(const bf16x8*)(wj + kf * 32);
            acc[jt] = __builtin_amdgcn_mfma_f32_16x16x32_bf16(a[kf], bf, acc[jt], 0, 0, 0);
        }
    }

    #pragma unroll
    for (int jt = 0; jt < 4; ++jt) {
        const int col = c0 + jt * 16 + row;
        #pragma unroll
        for (int r = 0; r < 4; ++r) {
            int n = nBase + r;
            if (n < n_nodes) {
                float agg = acc[jt][r] + dgO[r] * bc[jt];
                S[(size_t)n * HD + col] = fast_sigmoid(agg) + fast_softplus(hv[jt][r]);
            }
        }
    }
}

__global__ __launch_bounds__(256) void mpnn_scatter(
    const float* __restrict__ h, const int* __restrict__ src,
    const int* __restrict__ dst, float* __restrict__ S,
    int* __restrict__ deg, int n_edges)
{
    int gid = blockIdx.x * 256 + threadIdx.x;
    int e = gid >> 5;
    if (e >= n_edges) return;
    int lane = gid & 31;
    int s = src[e], d = dst[e];
    float4 v = *(const float4*)(h + (size_t)s * HD + lane * 4);
    float* srow = S + (size_t)d * HD + lane * 4;
    atomicAdd(srow + 0, v.x);
    atomicAdd(srow + 1, v.y);
    atomicAdd(srow + 2, v.z);
    atomicAdd(srow + 3, v.w);
    if (lane == 0) atomicAdd(deg + d, 1);
}

__global__ __launch_bounds__(256) void mpnn_node_f32(
    const float* __restrict__ h, const float* __restrict__ W,
    const float* __restrict__ b, const int* __restrict__ deg,
    float* __restrict__ S, int n_nodes)
{
    const int j = threadIdx.x & (HD - 1);
    const int g = threadIdx.x >> 7;
    const int n0 = blockIdx.x * NPB + g * RPT;

    float accS[RPT], accH[RPT];
    #pragma unroll
    for (int r = 0; r < RPT; ++r) { accS[r] = 0.f; accH[r] = 0.f; }

    int rmax = n_nodes - n0;
    if (rmax > RPT) rmax = RPT;
    if (rmax < 0) rmax = 0;

    for (int k = 0; k < HD; k += 4) {
        float w0 = W[(k + 0) * HD + j], w1 = W[(k + 1) * HD + j];
        float w2 = W[(k + 2) * HD + j], w3 = W[(k + 3) * HD + j];
        #pragma unroll
        for (int r = 0; r < RPT; ++r) if (r < rmax) {
            float4 a = *(const float4*)(S + (size_t)(n0 + r) * HD + k);
            accS[r] = fmaf(a.x, w0, fmaf(a.y, w1, fmaf(a.z, w2, fmaf(a.w, w3, accS[r]))));
        }
    }
    for (int k = 0; k < HD; k += 4) {
        float w0 = W[(HD + k + 0) * HD + j], w1 = W[(HD + k + 1) * HD + j];
        float w2 = W[(HD + k + 2) * HD + j], w3 = W[(HD + k + 3) * HD + j];
        #pragma unroll
        for (int r = 0; r < RPT; ++r) if (r < rmax) {
            float4 a = *(const float4*)(h + (size_t)(n0 + r) * HD + k);
            accH[r] = fmaf(a.x, w0, fmaf(a.y, w1, fmaf(a.z, w2, fmaf(a.w, w3, accH[r]))));
        }
    }
    __syncthreads();
    #pragma unroll
    for (int r = 0; r < RPT; ++r) if (r < rmax) {
        int n = n0 + r;
        float dg = (float)deg[n];
        float agg = accS[r] + dg * (accH[r] + b[j]);
        float hvv = h[(size_t)n * HD + j];
        S[(size_t)n * HD + j] = fast_sigmoid(agg) + fast_softplus(hvv);
    }
}

extern "C" void kernel_launch(void* const* d_in, const int* in_sizes, int n_in,
                              void* d_out, int out_size, void* d_ws, size_t ws_size,
                              hipStream_t stream)
{
    const float* h   = (const float*)d_in[0];
    const int*   src = (const int*)d_in[1];
    const int*   dst = (const int*)d_in[2];
    const float* W   = (const float*)d_in[3];
    const float* b   = (const float*)d_in[4];
    float* S = (float*)d_out;

    const int n_nodes = in_sizes[0] / HD;
    const int n_edges = in_sizes[1];
    const int WT_INTS = 2 * HD * HD / 2;            // 32768 shorts = 16384 ints
    const int nb = (n_nodes + 1023) / 1024;

    const size_t base_ints = (size_t)3 * n_nodes + 1 + n_edges + WT_INTS + nb;
    const size_t need_top  = (base_ints + (size_t)n_nodes * HD) * sizeof(int); // + hb + Sb
    const size_t need_full = base_ints * sizeof(int);
    const size_t need_mid  = ((size_t)n_nodes + WT_INTS) * sizeof(int);
    const int mblocks = (n_nodes + 31) / 32;

    if (ws_size >= need_top) {
        // CSR + bf16 gather + bf16-S MFMA
        int* deg   = (int*)d_ws;
        int* off   = deg + n_nodes;                 // n_nodes + 1
        int* cur   = off + n_nodes + 1;             // n_nodes
        int* elist = cur + n_nodes;                 // n_edges
        short* Wt  = (short*)(elist + n_edges);     // 32768 shorts
        int* bsum  = (int*)(Wt + 2 * HD * HD);      // nb
        short* hb  = (short*)(bsum + nb);           // n_nodes*HD bf16
        short* Sb  = hb + (size_t)n_nodes * HD;     // n_nodes*HD bf16

        hipMemsetAsync(deg, 0, (size_t)n_nodes * sizeof(int), stream);
        prep<<<3200, 256, 0, stream>>>(W, Wt, h, hb, dst, deg, n_nodes, n_edges);

        scan_blocks<<<nb, 1024, 0, stream>>>(deg, off, bsum, n_nodes);
        scan_partials<<<1, 64, 0, stream>>>(bsum, nb);
        scan_apply<<<nb, 1024, 0, stream>>>(off, cur, bsum, n_nodes, n_edges);

        edge_fill<<<(n_edges + 255) / 256, 256, 0, stream>>>(src, dst, cur, elist, n_edges);

        const int gblocks = (int)(((long long)n_nodes * 16 + 255) / 256);
        node_gather_bf16<<<gblocks, 256, 0, stream>>>(hb, off, elist, Sb, n_nodes);

        mpnn_node_mfma_sb<<<mblocks, 256, 0, stream>>>(h, Sb, Wt, b, deg, S, n_nodes);
    } else if (ws_size >= need_full) {
        // CSR + f32 gather + MFMA (R6 path)
        int* deg   = (int*)d_ws;
        int* off   = deg + n_nodes;
        int* cur   = off + n_nodes + 1;
        int* elist = cur + n_nodes;
        short* Wt  = (short*)(elist + n_edges);
        int* bsum  = (int*)(Wt + 2 * HD * HD);

        hipMemsetAsync(deg, 0, (size_t)n_nodes * sizeof(int), stream);
        wt_convert<<<(2 * HD * HD) / 256, 256, 0, stream>>>(W, Wt);
        edge_hist<<<(n_edges + 255) / 256, 256, 0, stream>>>(dst, deg, n_edges);

        scan_blocks<<<nb, 1024, 0, stream>>>(deg, off, bsum, n_nodes);
        scan_partials<<<1, 64, 0, stream>>>(bsum, nb);
        scan_apply<<<nb, 1024, 0, stream>>>(off, cur, bsum, n_nodes, n_edges);

        edge_fill<<<(n_edges + 255) / 256, 256, 0, stream>>>(src, dst, cur, elist, n_edges);

        const int gblocks = (int)(((long long)n_nodes * 32 + 255) / 256);
        node_gather<<<gblocks, 256, 0, stream>>>(h, off, elist, S, n_nodes);

        mpnn_node_mfma<<<mblocks, 256, 0, stream>>>(h, Wt, b, deg, S, n_nodes);
    } else if (ws_size >= need_mid) {
        int* deg  = (int*)d_ws;
        short* Wt = (short*)(deg + n_nodes);
        hipMemsetAsync(d_out, 0, (size_t)n_nodes * HD * sizeof(float), stream);
        hipMemsetAsync(deg, 0, (size_t)n_nodes * sizeof(int), stream);
        wt_convert<<<(2 * HD * HD) / 256, 256, 0, stream>>>(W, Wt);
        const int sblocks = (int)(((long long)n_edges * 32 + 255) / 256);
        mpnn_scatter<<<sblocks, 256, 0, stream>>>(h, src, dst, S, deg, n_edges);
        mpnn_node_mfma<<<mblocks, 256, 0, stream>>>(h, Wt, b, deg, S, n_nodes);
    } else {
        int* deg = (int*)d_ws;
        hipMemsetAsync(d_out, 0, (size_t)n_nodes * HD * sizeof(float), stream);
        hipMemsetAsync(deg, 0, (size_t)n_nodes * sizeof(int), stream);
        const int sblocks = (int)(((long long)n_edges * 32 + 255) / 256);
        mpnn_scatter<<<sblocks, 256, 0, stream>>>(h, src, dst, S, deg, n_edges);
        const int nblocks = (n_nodes + NPB - 1) / NPB;
        mpnn_node_f32<<<nblocks, 256, 0, stream>>>(h, W, b, deg, S, n_nodes);
    }
}

// Round 8
// 148.722 us; speedup vs baseline: 9.2788x; 1.0162x over previous
//
#include <hip/hip_runtime.h>
#include <math.h>

#define HD 128
#define MT 32    // nodes per fused block
#define NPB 16
#define RPT 8

typedef __attribute__((ext_vector_type(8))) short bf16x8;
typedef __attribute__((ext_vector_type(4))) float f32x4;

__device__ inline short f2bf(float x) {   // RTNE f32->bf16
    union { float f; unsigned u; } v; v.f = x;
    unsigned r = v.u + 0x7fff + ((v.u >> 16) & 1);
    return (short)(r >> 16);
}
__device__ inline float bf2f(short x) {
    union { unsigned u; float f; } v;
    v.u = ((unsigned)(unsigned short)x) << 16;
    return v.f;
}

#define LOG2E 1.4426950408889634f
#define LN2   0.6931471805599453f

__device__ inline float fast_sigmoid(float x) {
    return __builtin_amdgcn_rcpf(1.0f + __builtin_amdgcn_exp2f(-LOG2E * x));
}
__device__ inline float fast_softplus(float x) {
    float t = __builtin_amdgcn_exp2f(-LOG2E * fabsf(x));
    return fmaxf(x, 0.0f) + LN2 * __builtin_amdgcn_logf(1.0f + t);
}

__device__ inline void accum8(float* a, const uint4 u) {  // += 8 bf16 packed in uint4
    a[0] += __uint_as_float(u.x << 16);
    a[1] += __uint_as_float(u.x & 0xffff0000u);
    a[2] += __uint_as_float(u.y << 16);
    a[3] += __uint_as_float(u.y & 0xffff0000u);
    a[4] += __uint_as_float(u.z << 16);
    a[5] += __uint_as_float(u.z & 0xffff0000u);
    a[6] += __uint_as_float(u.w << 16);
    a[7] += __uint_as_float(u.w & 0xffff0000u);
}

// ---------- fused prep: Wt repack + h->bf16 + degree histogram ----------

__global__ __launch_bounds__(256) void prep(
    const float* __restrict__ W, short* __restrict__ Wt,
    const float* __restrict__ h, short* __restrict__ hb,
    const int* __restrict__ dst, int* __restrict__ deg,
    int n_nodes, int n_edges)
{
    const int tid = blockIdx.x * 256 + threadIdx.x;
    const int total = gridDim.x * 256;

    const int hitems = n_nodes * HD / 8;
    for (int i = tid; i < hitems; i += total) {
        const float4* p = (const float4*)(h + (size_t)i * 8);
        float4 x = p[0], y = p[1];
        bf16x8 t = { f2bf(x.x), f2bf(x.y), f2bf(x.z), f2bf(x.w),
                     f2bf(y.x), f2bf(y.y), f2bf(y.z), f2bf(y.w) };
        *(bf16x8*)(hb + (size_t)i * 8) = t;
    }
    for (int i = tid; i < 2 * HD * HD; i += total) {
        int j = i >> 8, k = i & 255;
        Wt[i] = f2bf(W[k * HD + j]);
    }
    for (int e = tid; e < n_edges; e += total)
        atomicAdd(&deg[dst[e]], 1);
}

// ---------------- hierarchical scan ----------------

__global__ __launch_bounds__(1024) void scan_blocks(
    const int* __restrict__ deg, int* __restrict__ off,
    int* __restrict__ bsum, int n_nodes)
{
    __shared__ int wtot[16];
    const int t = threadIdx.x;
    const int lane = t & 63;
    const int wid = t >> 6;
    int idx = blockIdx.x * 1024 + t;
    int v = (idx < n_nodes) ? deg[idx] : 0;
    int incl = v;
    #pragma unroll
    for (int o = 1; o < 64; o <<= 1) {
        int y = __shfl_up(incl, o, 64);
        if (lane >= o) incl += y;
    }
    if (lane == 63) wtot[wid] = incl;
    __syncthreads();
    if (wid == 0) {
        int w = (lane < 16) ? wtot[lane] : 0;
        int wi = w;
        #pragma unroll
        for (int o = 1; o < 16; o <<= 1) {
            int y = __shfl_up(wi, o, 64);
            if (lane >= o) wi += y;
        }
        if (lane < 16) wtot[lane] = wi - w;
    }
    __syncthreads();
    int excl = wtot[wid] + incl - v;
    if (idx < n_nodes) off[idx] = excl;
    if (t == 1023) bsum[blockIdx.x] = wtot[15] + incl;
}

__global__ __launch_bounds__(64) void scan_partials(int* __restrict__ bsum, int nb)
{
    const int lane = threadIdx.x;
    int carry = 0;
    for (int base = 0; base < nb; base += 64) {
        int i = base + lane;
        int v = (i < nb) ? bsum[i] : 0;
        int incl = v;
        #pragma unroll
        for (int o = 1; o < 64; o <<= 1) {
            int y = __shfl_up(incl, o, 64);
            if (lane >= o) incl += y;
        }
        if (i < nb) bsum[i] = carry + incl - v;
        carry += __shfl(incl, 63, 64);
    }
}

__global__ __launch_bounds__(1024) void scan_apply(
    int* __restrict__ off, int* __restrict__ cur,
    const int* __restrict__ bsum, int n_nodes, int n_edges)
{
    int idx = blockIdx.x * 1024 + threadIdx.x;
    if (idx < n_nodes) {
        int v = off[idx] + bsum[blockIdx.x];
        off[idx] = v;
        cur[idx] = v;
    }
    if (idx == 0) off[n_nodes] = n_edges;
}

__global__ __launch_bounds__(256) void edge_fill(
    const int* __restrict__ src, const int* __restrict__ dst,
    int* __restrict__ cur, int* __restrict__ elist, int n_edges)
{
    int e = blockIdx.x * 256 + threadIdx.x;
    if (e < n_edges) {
        int d = dst[e];
        int pos = atomicAdd(&cur[d], 1);
        elist[pos] = src[e];
    }
}

// ============ fused gather + MFMA + epilogue, MT=32 nodes/block ============
// Phase 1: 8 lanes/node gather-sum hb rows (f32 acc), build A-panel
//          X[nl][0:128]=bf16(S), X[nl][128:256]=bf16(deg*hb) in LDS.
// Phase 2: 4 waves, 16 rows x 64 cols each; A from LDS, B=Wt from L2;
//          epilogue sigmoid(agg)+softplus(hb) -> out.
// A/B both use k = (lane>>4)*8 + slot; C/D: col=lane&15, row=(lane>>4)*4+reg.
__global__ __launch_bounds__(256) void gather_mfma(
    const short* __restrict__ hb,    // [N][128] bf16
    const int* __restrict__ off,     // [N+1]
    const int* __restrict__ elist,   // [E]
    const short* __restrict__ Wt,    // [128][256] bf16
    const float* __restrict__ bias,  // [128] f32
    float* __restrict__ out,         // [N][128] f32
    int n_nodes)
{
    __shared__ short X[MT][264];     // row stride 528B (132 dwords) - conflict-light
    __shared__ int sdeg[MT];

    const int t = threadIdx.x;
    const int m0blk = blockIdx.x * MT;

    // ---------------- phase 1: gather ----------------
    {
        const int nl = t >> 3;           // 0..31 node-local
        const int l8 = t & 7;            // 0..7, owns cols [l8*16, l8*16+16)
        const int n = m0blk + nl;
        int beg = 0, end = 0;
        if (n < n_nodes) { beg = off[n]; end = off[n + 1]; }
        const size_t co = (size_t)(l8 * 16);

        float a0[16], a1[16];
        #pragma unroll
        for (int q = 0; q < 16; ++q) { a0[q] = 0.f; a1[q] = 0.f; }

        int i = beg;
        for (; i + 4 <= end; i += 4) {
            int s0 = elist[i], s1 = elist[i + 1], s2 = elist[i + 2], s3 = elist[i + 3];
            const uint4* p0 = (const uint4*)(hb + (size_t)s0 * HD + co);
            const uint4* p1 = (const uint4*)(hb + (size_t)s1 * HD + co);
            const uint4* p2 = (const uint4*)(hb + (size_t)s2 * HD + co);
            const uint4* p3 = (const uint4*)(hb + (size_t)s3 * HD + co);
            uint4 x0 = p0[0], y0 = p0[1], x1 = p1[0], y1 = p1[1];
            uint4 x2 = p2[0], y2 = p2[1], x3 = p3[0], y3 = p3[1];
            accum8(a0, x0); accum8(a0 + 8, y0);
            accum8(a1, x1); accum8(a1 + 8, y1);
            accum8(a0, x2); accum8(a0 + 8, y2);
            accum8(a1, x3); accum8(a1 + 8, y3);
        }
        for (; i < end; ++i) {
            int s0 = elist[i];
            const uint4* p0 = (const uint4*)(hb + (size_t)s0 * HD + co);
            uint4 x0 = p0[0], y0 = p0[1];
            accum8(a0, x0); accum8(a0 + 8, y0);
        }

        // Sb tile
        bf16x8 sb0, sb1;
        #pragma unroll
        for (int q = 0; q < 8; ++q) sb0[q] = f2bf(a0[q] + a1[q]);
        #pragma unroll
        for (int q = 0; q < 8; ++q) sb1[q] = f2bf(a0[8 + q] + a1[8 + q]);
        *(bf16x8*)&X[nl][co] = sb0;
        *(bf16x8*)&X[nl][co + 8] = sb1;

        // deg*hb tile (deg = end-beg; 0 for tail/isolated nodes)
        float dg = (float)(end - beg);
        int nc = (n < n_nodes) ? n : 0;
        const uint4* ph = (const uint4*)(hb + (size_t)nc * HD + co);
        uint4 hx = ph[0], hy = ph[1];
        float hf[16];
        hf[0] = __uint_as_float(hx.x << 16); hf[1] = __uint_as_float(hx.x & 0xffff0000u);
        hf[2] = __uint_as_float(hx.y << 16); hf[3] = __uint_as_float(hx.y & 0xffff0000u);
        hf[4] = __uint_as_float(hx.z << 16); hf[5] = __uint_as_float(hx.z & 0xffff0000u);
        hf[6] = __uint_as_float(hx.w << 16); hf[7] = __uint_as_float(hx.w & 0xffff0000u);
        hf[8] = __uint_as_float(hy.x << 16); hf[9] = __uint_as_float(hy.x & 0xffff0000u);
        hf[10] = __uint_as_float(hy.y << 16); hf[11] = __uint_as_float(hy.y & 0xffff0000u);
        hf[12] = __uint_as_float(hy.z << 16); hf[13] = __uint_as_float(hy.z & 0xffff0000u);
        hf[14] = __uint_as_float(hy.w << 16); hf[15] = __uint_as_float(hy.w & 0xffff0000u);
        bf16x8 hd0, hd1;
        #pragma unroll
        for (int q = 0; q < 8; ++q) hd0[q] = f2bf(dg * hf[q]);
        #pragma unroll
        for (int q = 0; q < 8; ++q) hd1[q] = f2bf(dg * hf[8 + q]);
        *(bf16x8*)&X[nl][128 + co] = hd0;
        *(bf16x8*)&X[nl][128 + co + 8] = hd1;

        if (l8 == 0) sdeg[nl] = end - beg;
    }

    __syncthreads();

    // ---------------- phase 2: MFMA + epilogue ----------------
    {
        const int lane = t & 63;
        const int wv = t >> 6;               // 0..3
        const int Rbase = (wv >> 1) * 16;    // m-half
        const int c0 = (wv & 1) * 64;        // col-half
        const int row = lane & 15;
        const int g = lane >> 4;

        bf16x8 a[8];
        #pragma unroll
        for (int kf = 0; kf < 8; ++kf)
            a[kf] = *(const bf16x8*)&X[Rbase + row][kf * 32 + g * 8];

        f32x4 acc[4];
        #pragma unroll
        for (int jt = 0; jt < 4; ++jt) acc[jt] = (f32x4){0.f, 0.f, 0.f, 0.f};

        #pragma unroll
        for (int jt = 0; jt < 4; ++jt) {
            const short* wj = Wt + (size_t)(c0 + jt * 16 + row) * 256 + g * 8;
            #pragma unroll
            for (int kf = 0; kf < 8; ++kf) {
                bf16x8 bf = *(const bf16x8*)(wj + kf * 32);
                acc[jt] = __builtin_amdgcn_mfma_f32_16x16x32_bf16(a[kf], bf, acc[jt], 0, 0, 0);
            }
        }

        const int nBase = m0blk + Rbase + g * 4;
        float dgO[4];
        #pragma unroll
        for (int r = 0; r < 4; ++r) dgO[r] = (float)sdeg[Rbase + g * 4 + r];

        #pragma unroll
        for (int jt = 0; jt < 4; ++jt) {
            const int col = c0 + jt * 16 + row;
            const float bc = bias[col];
            #pragma unroll
            for (int r = 0; r < 4; ++r) {
                int n = nBase + r;
                if (n < n_nodes) {
                    float hvv = bf2f(hb[(size_t)n * HD + col]);
                    float agg = acc[jt][r] + dgO[r] * bc;
                    out[(size_t)n * HD + col] = fast_sigmoid(agg) + fast_softplus(hvv);
                }
            }
        }
    }
}

// ================== fallback tiers (proven R6 path) ==================

__global__ __launch_bounds__(256) void edge_hist(
    const int* __restrict__ dst, int* __restrict__ deg, int n_edges)
{
    int e = blockIdx.x * 256 + threadIdx.x;
    if (e < n_edges) atomicAdd(&deg[dst[e]], 1);
}

__global__ __launch_bounds__(256) void wt_convert(
    const float* __restrict__ W, short* __restrict__ Wt)
{
    int idx = blockIdx.x * 256 + threadIdx.x;
    int j = idx >> 8;
    int k = idx & 255;
    Wt[idx] = f2bf(W[k * HD + j]);
}

__global__ __launch_bounds__(256) void node_gather(
    const float* __restrict__ h, const int* __restrict__ off,
    const int* __restrict__ elist, float* __restrict__ S, int n_nodes)
{
    int g = (blockIdx.x * 256 + threadIdx.x) >> 5;
    int lane = threadIdx.x & 31;
    if (g >= n_nodes) return;
    int beg = off[g], end = off[g + 1];
    float4 a0 = {0,0,0,0}, a1 = {0,0,0,0}, a2 = {0,0,0,0}, a3 = {0,0,0,0};
    const size_t lo = (size_t)(lane * 4);
    int i = beg;
    for (; i + 4 <= end; i += 4) {
        int s0 = elist[i], s1 = elist[i+1], s2 = elist[i+2], s3 = elist[i+3];
        float4 v0 = *(const float4*)(h + (size_t)s0 * HD + lo);
        float4 v1 = *(const float4*)(h + (size_t)s1 * HD + lo);
        float4 v2 = *(const float4*)(h + (size_t)s2 * HD + lo);
        float4 v3 = *(const float4*)(h + (size_t)s3 * HD + lo);
        a0.x += v0.x; a0.y += v0.y; a0.z += v0.z; a0.w += v0.w;
        a1.x += v1.x; a1.y += v1.y; a1.z += v1.z; a1.w += v1.w;
        a2.x += v2.x; a2.y += v2.y; a2.z += v2.z; a2.w += v2.w;
        a3.x += v3.x; a3.y += v3.y; a3.z += v3.z; a3.w += v3.w;
    }
    for (; i < end; ++i) {
        int s0 = elist[i];
        float4 v0 = *(const float4*)(h + (size_t)s0 * HD + lo);
        a0.x += v0.x; a0.y += v0.y; a0.z += v0.z; a0.w += v0.w;
    }
    float4 acc;
    acc.x = (a0.x + a1.x) + (a2.x + a3.x);
    acc.y = (a0.y + a1.y) + (a2.y + a3.y);
    acc.z = (a0.z + a1.z) + (a2.z + a3.z);
    acc.w = (a0.w + a1.w) + (a2.w + a3.w);
    *(float4*)(S + (size_t)g * HD + lo) = acc;
}

__global__ __launch_bounds__(256) void mpnn_node_mfma(
    const float* __restrict__ h,
    const short* __restrict__ Wt,
    const float* __restrict__ bias,
    const int* __restrict__ deg,
    float* __restrict__ S,
    int n_nodes)
{
    const int lane = threadIdx.x & 63;
    const int wv = threadIdx.x >> 6;
    const int m0 = blockIdx.x * 32 + (wv >> 1) * 16;
    const int c0 = (wv & 1) * 64;
    if (m0 >= n_nodes) return;
    const int row = lane & 15;
    const int g = lane >> 4;

    const int nBase = m0 + g * 4;
    float dgO[4], hv[4][4], bc[4];
    #pragma unroll
    for (int r = 0; r < 4; ++r) {
        int n = nBase + r;
        int nc = (n < n_nodes) ? n : (n_nodes - 1);
        dgO[r] = (float)deg[nc];
        #pragma unroll
        for (int jt = 0; jt < 4; ++jt)
            hv[jt][r] = h[(size_t)nc * HD + c0 + jt * 16 + row];
    }
    #pragma unroll
    for (int jt = 0; jt < 4; ++jt) bc[jt] = bias[c0 + jt * 16 + row];

    int mA = m0 + row;
    if (mA > n_nodes - 1) mA = n_nodes - 1;
    const float dgA = (float)deg[mA];

    bf16x8 a[8];
    #pragma unroll
    for (int kf = 0; kf < 4; ++kf) {
        const float4* p = (const float4*)(S + (size_t)mA * HD + kf * 32 + g * 8);
        float4 x = p[0], y = p[1];
        bf16x8 t = { f2bf(x.x), f2bf(x.y), f2bf(x.z), f2bf(x.w),
                     f2bf(y.x), f2bf(y.y), f2bf(y.z), f2bf(y.w) };
        a[kf] = t;
    }
    #pragma unroll
    for (int kf = 0; kf < 4; ++kf) {
        const float4* p = (const float4*)(h + (size_t)mA * HD + kf * 32 + g * 8);
        float4 x = p[0], y = p[1];
        bf16x8 t = { f2bf(dgA * x.x), f2bf(dgA * x.y), f2bf(dgA * x.z), f2bf(dgA * x.w),
                     f2bf(dgA * y.x), f2bf(dgA * y.y), f2bf(dgA * y.z), f2bf(dgA * y.w) };
        a[4 + kf] = t;
    }

    f32x4 acc[4];
    #pragma unroll
    for (int jt = 0; jt < 4; ++jt) acc[jt] = (f32x4){0.f, 0.f, 0.f, 0.f};

    #pragma unroll
    for (int jt = 0; jt < 4; ++jt) {
        const short* wj = Wt + (size_t)(c0 + jt * 16 + row) * 256 + g * 8;
        #pragma unroll
        for (int kf = 0; kf < 8; ++kf) {
            bf16x8 bf = *(const bf16x8*)(wj + kf * 32);
            acc[jt] = __builtin_amdgcn_mfma_f32_16x16x32_bf16(a[kf], bf, acc[jt], 0, 0, 0);
        }
    }

    #pragma unroll
    for (int jt = 0; jt < 4; ++jt) {
        const int col = c0 + jt * 16 + row;
        #pragma unroll
        for (int r = 0; r < 4; ++r) {
            int n = nBase + r;
            if (n < n_nodes) {
                float agg = acc[jt][r] + dgO[r] * bc[jt];
                S[(size_t)n * HD + col] = fast_sigmoid(agg) + fast_softplus(hv[jt][r]);
            }
        }
    }
}

__global__ __launch_bounds__(256) void mpnn_scatter(
    const float* __restrict__ h, const int* __restrict__ src,
    const int* __restrict__ dst, float* __restrict__ S,
    int* __restrict__ deg, int n_edges)
{
    int gid = blockIdx.x * 256 + threadIdx.x;
    int e = gid >> 5;
    if (e >= n_edges) return;
    int lane = gid & 31;
    int s = src[e], d = dst[e];
    float4 v = *(const float4*)(h + (size_t)s * HD + lane * 4);
    float* srow = S + (size_t)d * HD + lane * 4;
    atomicAdd(srow + 0, v.x);
    atomicAdd(srow + 1, v.y);
    atomicAdd(srow + 2, v.z);
    atomicAdd(srow + 3, v.w);
    if (lane == 0) atomicAdd(deg + d, 1);
}

__global__ __launch_bounds__(256) void mpnn_node_f32(
    const float* __restrict__ h, const float* __restrict__ W,
    const float* __restrict__ b, const int* __restrict__ deg,
    float* __restrict__ S, int n_nodes)
{
    const int j = threadIdx.x & (HD - 1);
    const int g = threadIdx.x >> 7;
    const int n0 = blockIdx.x * NPB + g * RPT;

    float accS[RPT], accH[RPT];
    #pragma unroll
    for (int r = 0; r < RPT; ++r) { accS[r] = 0.f; accH[r] = 0.f; }

    int rmax = n_nodes - n0;
    if (rmax > RPT) rmax = RPT;
    if (rmax < 0) rmax = 0;

    for (int k = 0; k < HD; k += 4) {
        float w0 = W[(k + 0) * HD + j], w1 = W[(k + 1) * HD + j];
        float w2 = W[(k + 2) * HD + j], w3 = W[(k + 3) * HD + j];
        #pragma unroll
        for (int r = 0; r < RPT; ++r) if (r < rmax) {
            float4 a = *(const float4*)(S + (size_t)(n0 + r) * HD + k);
            accS[r] = fmaf(a.x, w0, fmaf(a.y, w1, fmaf(a.z, w2, fmaf(a.w, w3, accS[r]))));
        }
    }
    for (int k = 0; k < HD; k += 4) {
        float w0 = W[(HD + k + 0) * HD + j], w1 = W[(HD + k + 1) * HD + j];
        float w2 = W[(HD + k + 2) * HD + j], w3 = W[(HD + k + 3) * HD + j];
        #pragma unroll
        for (int r = 0; r < RPT; ++r) if (r < rmax) {
            float4 a = *(const float4*)(h + (size_t)(n0 + r) * HD + k);
            accH[r] = fmaf(a.x, w0, fmaf(a.y, w1, fmaf(a.z, w2, fmaf(a.w, w3, accH[r]))));
        }
    }
    __syncthreads();
    #pragma unroll
    for (int r = 0; r < RPT; ++r) if (r < rmax) {
        int n = n0 + r;
        float dg = (float)deg[n];
        float agg = accS[r] + dg * (accH[r] + b[j]);
        float hvv = h[(size_t)n * HD + j];
        S[(size_t)n * HD + j] = fast_sigmoid(agg) + fast_softplus(hvv);
    }
}

extern "C" void kernel_launch(void* const* d_in, const int* in_sizes, int n_in,
                              void* d_out, int out_size, void* d_ws, size_t ws_size,
                              hipStream_t stream)
{
    const float* h   = (const float*)d_in[0];
    const int*   src = (const int*)d_in[1];
    const int*   dst = (const int*)d_in[2];
    const float* W   = (const float*)d_in[3];
    const float* b   = (const float*)d_in[4];
    float* S = (float*)d_out;

    const int n_nodes = in_sizes[0] / HD;
    const int n_edges = in_sizes[1];
    const int WT_INTS = 2 * HD * HD / 2;
    const int nb = (n_nodes + 1023) / 1024;

    // ---- 16B-aligned ws layout for the fused path ----
    char* p = (char*)d_ws;
    auto align16 = [](char* q) { return (char*)(((uintptr_t)q + 15) & ~(uintptr_t)15); };
    p = align16(p); int* deg = (int*)p;    p += (size_t)n_nodes * 4;
    p = align16(p); int* off = (int*)p;    p += ((size_t)n_nodes + 1) * 4;
    p = align16(p); int* cur = (int*)p;    p += (size_t)n_nodes * 4;
    p = align16(p); int* elist = (int*)p;  p += (size_t)n_edges * 4;
    p = align16(p); short* Wt = (short*)p; p += (size_t)2 * HD * HD * 2;
    p = align16(p); int* bsum = (int*)p;   p += (size_t)nb * 4;
    p = align16(p); short* hb = (short*)p; p += (size_t)n_nodes * HD * 2;
    const size_t need_top = (size_t)(p - (char*)d_ws);

    const size_t need_full = ((size_t)3 * n_nodes + 1 + n_edges + WT_INTS + nb + 8) * sizeof(int);
    const size_t need_mid  = ((size_t)n_nodes + WT_INTS) * sizeof(int);

    if (ws_size >= need_top) {
        // CSR + fused gather/MFMA/epilogue
        hipMemsetAsync(deg, 0, (size_t)n_nodes * sizeof(int), stream);
        prep<<<3200, 256, 0, stream>>>(W, Wt, h, hb, dst, deg, n_nodes, n_edges);

        scan_blocks<<<nb, 1024, 0, stream>>>(deg, off, bsum, n_nodes);
        scan_partials<<<1, 64, 0, stream>>>(bsum, nb);
        scan_apply<<<nb, 1024, 0, stream>>>(off, cur, bsum, n_nodes, n_edges);

        edge_fill<<<(n_edges + 255) / 256, 256, 0, stream>>>(src, dst, cur, elist, n_edges);

        const int fblocks = (n_nodes + MT - 1) / MT;
        gather_mfma<<<fblocks, 256, 0, stream>>>(hb, off, elist, Wt, b, S, n_nodes);
    } else if (ws_size >= need_full) {
        // CSR + f32 gather + MFMA (R6 path)
        int* deg2   = (int*)d_ws;
        int* off2   = deg2 + n_nodes;
        int* cur2   = off2 + n_nodes + 1;
        int* elist2 = cur2 + n_nodes;
        short* Wt2  = (short*)(elist2 + n_edges);
        int* bsum2  = (int*)(Wt2 + 2 * HD * HD);

        hipMemsetAsync(deg2, 0, (size_t)n_nodes * sizeof(int), stream);
        wt_convert<<<(2 * HD * HD) / 256, 256, 0, stream>>>(W, Wt2);
        edge_hist<<<(n_edges + 255) / 256, 256, 0, stream>>>(dst, deg2, n_edges);

        scan_blocks<<<nb, 1024, 0, stream>>>(deg2, off2, bsum2, n_nodes);
        scan_partials<<<1, 64, 0, stream>>>(bsum2, nb);
        scan_apply<<<nb, 1024, 0, stream>>>(off2, cur2, bsum2, n_nodes, n_edges);

        edge_fill<<<(n_edges + 255) / 256, 256, 0, stream>>>(src, dst, cur2, elist2, n_edges);

        const int gblocks = (int)(((long long)n_nodes * 32 + 255) / 256);
        node_gather<<<gblocks, 256, 0, stream>>>(h, off2, elist2, S, n_nodes);

        const int mblocks = (n_nodes + 31) / 32;
        mpnn_node_mfma<<<mblocks, 256, 0, stream>>>(h, Wt2, b, deg2, S, n_nodes);
    } else if (ws_size >= need_mid) {
        int* deg2  = (int*)d_ws;
        short* Wt2 = (short*)(deg2 + n_nodes);
        hipMemsetAsync(d_out, 0, (size_t)n_nodes * HD * sizeof(float), stream);
        hipMemsetAsync(deg2, 0, (size_t)n_nodes * sizeof(int), stream);
        wt_convert<<<(2 * HD * HD) / 256, 256, 0, stream>>>(W, Wt2);
        const int sblocks = (int)(((long long)n_edges * 32 + 255) / 256);
        mpnn_scatter<<<sblocks, 256, 0, stream>>>(h, src, dst, S, deg2, n_edges);
        const int mblocks = (n_nodes + 31) / 32;
        mpnn_node_mfma<<<mblocks, 256, 0, stream>>>(h, Wt2, b, deg2, S, n_nodes);
    } else {
        int* deg2 = (int*)d_ws;
        hipMemsetAsync(d_out, 0, (size_t)n_nodes * HD * sizeof(float), stream);
        hipMemsetAsync(deg2, 0, (size_t)n_nodes * sizeof(int), stream);
        const int sblocks = (int)(((long long)n_edges * 32 + 255) / 256);
        mpnn_scatter<<<sblocks, 256, 0, stream>>>(h, src, dst, S, deg2, n_edges);
        const int nblocks = (n_nodes + NPB - 1) / NPB;
        mpnn_node_f32<<<nblocks, 256, 0, stream>>>(h, W, b, deg2, S, n_nodes);
    }
}